// Round 7
// baseline (2588.176 us; speedup 1.0000x reference)
//
#include <hip/hip_runtime.h>
#include <math.h>

#define EPSF 1e-8f

constexpr int CB = 16;      // batch
constexpr int CT = 1024;    // time
constexpr int CN = 512;     // nodes
constexpr int CD = 512;     // hidden
constexpr int CIN = 1536;   // 3*N
constexpr int PB = CN * CN;
constexpr size_t SBTN = (size_t)CB * CT * CN;
constexpr size_t SBNN = (size_t)CB * PB;
constexpr long long PLX = 16777216LL;   // Xtp plane stride (u16 elems)

typedef __attribute__((ext_vector_type(8))) short bf16x8;
typedef __attribute__((ext_vector_type(4))) float f32x4;

__device__ inline unsigned short f2bf(float x) {   // RNE to bf16
  unsigned u = __float_as_uint(x);
  unsigned r = (u + 0x7fffu + ((u >> 16) & 1u)) >> 16;
  return (unsigned short)r;
}
__device__ inline float bf2f(unsigned short h) { return __uint_as_float(((unsigned)h) << 16); }

// async global->LDS, 16B per lane. LDS dest is wave-uniform base + lane*16.
__device__ inline void gl_lds16(const unsigned short* g, unsigned short* l) {
  __builtin_amdgcn_global_load_lds(
      (const __attribute__((address_space(1))) unsigned int*)g,
      (__attribute__((address_space(3))) unsigned int*)l, 16, 0, 0);
}

// SGPR broadcast of lane l's value (compile-time l in unrolled loops)
__device__ inline float rdlane(float v, int l) {
  return __int_as_float(__builtin_amdgcn_readlane(__float_as_int(v), l));
}

// ---------------- utility ----------------
__global__ void zero_k(float* p, int n) {
  int i = blockIdx.x * 256 + threadIdx.x;
  if (i < n) p[i] = 0.f;
}

// ---------------- column means ----------------
__global__ __launch_bounds__(256) void colmean_k(const float* __restrict__ x, float* __restrict__ ms) {
  int b = blockIdx.y;
  int n = blockIdx.x * 256 + threadIdx.x;
  int t0 = blockIdx.z * 256;
  const float* xb = x + (size_t)b * CT * CN + (size_t)t0 * CN + n;
  float s = 0.f;
  for (int t = 0; t < 256; ++t) s += xb[(size_t)t * CN];
  atomicAdd(&ms[b * CN + n], s);
}

// ---------------- centered transpose-pack: x (b,t,n) -> Xtp slot b (n,t) bf16 hi/lo ----------------
__global__ __launch_bounds__(256) void cpack_k(const float* __restrict__ x, const float* __restrict__ ms,
                                               unsigned short* __restrict__ Xtp) {
  __shared__ float t[64][65];
  int b = blockIdx.z, n0 = blockIdx.x * 64, t0 = blockIdx.y * 64;
  const float* xb = x + (size_t)b * CT * CN;
  for (int idx = threadIdx.x; idx < 4096; idx += 256) {
    int r = idx >> 6, c = idx & 63;
    t[r][c] = xb[(size_t)(t0 + r) * CN + n0 + c] - ms[b * CN + n0 + c] * (1.0f / CT);
  }
  __syncthreads();
  unsigned short* base = Xtp + (size_t)b * 524288;
  for (int idx = threadIdx.x; idx < 2048; idx += 256) {
    int nr = idx >> 5, tc = (idx & 31) * 2;
    float v0 = t[tc][nr], v1 = t[tc + 1][nr];
    unsigned short h0 = f2bf(v0), h1 = f2bf(v1);
    unsigned short l0 = f2bf(v0 - bf2f(h0)), l1 = f2bf(v1 - bf2f(h1));
    size_t off = (size_t)(n0 + nr) * 1024 + t0 + tc;
    *(unsigned int*)&base[off] = (unsigned int)h0 | ((unsigned int)h1 << 16);
    *(unsigned int*)&base[off + PLX] = (unsigned int)l0 | ((unsigned int)l1 << 16);
  }
}

// ---------------- Spearman ranks: merge-split bitonic, 1 column/wave, 8 columns/block ----------------
static __device__ inline unsigned long long shflx64(unsigned long long v, int m) {
  int lo = __shfl_xor((int)(unsigned)v, m, 64);
  int hi = __shfl_xor((int)(unsigned)(v >> 32), m, 64);
  return ((unsigned long long)(unsigned)hi << 32) | (unsigned)lo;
}

__global__ __launch_bounds__(512, 8) void ranks_k(const float* __restrict__ x, unsigned short* __restrict__ Xtp) {
  int b = blockIdx.y;
  int n0 = blockIdx.x * 8;
  __shared__ float stage[8][1032];
  const float* xb = x + (size_t)b * CT * CN + n0;
  for (int t = threadIdx.x; t < 1024; t += 512) {
    float4 v0 = *(const float4*)&xb[(size_t)t * CN];
    float4 v1 = *(const float4*)&xb[(size_t)t * CN + 4];
    stage[0][t] = v0.x; stage[1][t] = v0.y; stage[2][t] = v0.z; stage[3][t] = v0.w;
    stage[4][t] = v1.x; stage[5][t] = v1.y; stage[6][t] = v1.z; stage[7][t] = v1.w;
  }
  __syncthreads();
  const int wave = threadIdx.x >> 6;
  const int lane = threadIdx.x & 63;
  const int c = wave;
  {
    unsigned long long kv[16];
#pragma unroll
    for (int m = 0; m < 16; ++m) {
      int pos = m * 64 + lane;
      unsigned int u = __float_as_uint(stage[c][pos]);
      u = (u & 0x80000000u) ? ~u : (u | 0x80000000u);
      kv[m] = (((unsigned long long)u) << 32) | (unsigned)pos;
    }
#define CE_KV(a, bb, up) { bool sw_ = (up) ? (kv[a] > kv[bb]) : (kv[a] < kv[bb]); \
  if (sw_) { unsigned long long t_ = kv[a]; kv[a] = kv[bb]; kv[bb] = t_; } }
#pragma unroll
    for (int k2 = 2; k2 <= 16; k2 <<= 1) {
#pragma unroll
      for (int j2 = 8; j2 >= 1; j2 >>= 1) {
        if (j2 >= k2) continue;
#pragma unroll
        for (int t = 0; t < 16; ++t)
          if (!(t & j2)) { bool up2 = ((t & k2) == 0); CE_KV(t, t | j2, up2); }
      }
    }
#pragma unroll
    for (int k = 2; k <= 64; k <<= 1) {
#pragma unroll
      for (int j = 32; j >= 1; j >>= 1) {
        if (j >= k) continue;
        bool up = ((lane & k) == 0);
        bool isLow = ((lane & j) == 0);
        bool keepMin = (isLow == up);
        unsigned long long oth[16];
#pragma unroll
        for (int i = 0; i < 16; ++i) oth[i] = shflx64(kv[15 - i], j);
#pragma unroll
        for (int i = 0; i < 16; ++i) {
          unsigned long long o = oth[i];
          bool less = kv[i] < o;
          kv[i] = (less == keepMin) ? kv[i] : o;
        }
#pragma unroll
        for (int j2 = 8; j2 >= 1; j2 >>= 1)
#pragma unroll
          for (int t = 0; t < 16; ++t)
            if (!(t & j2)) CE_KV(t, t | j2, true);
      }
    }
#undef CE_KV
#pragma unroll
    for (int m = 0; m < 16; ++m) {
      unsigned int pos = (unsigned int)kv[m] & 1023u;
      stage[c][pos] = ((float)(lane * 16 + m + 1) - 512.5f) * (1.0f / 512.0f);
    }
  }
  __syncthreads();
  unsigned short* base = Xtp + (size_t)(16 + b) * 524288;
  for (int idx = threadIdx.x; idx < 4096; idx += 512) {
    int row = idx >> 9, t2 = (idx & 511) * 2;
    float v0 = stage[row][t2], v1 = stage[row][t2 + 1];
    unsigned short h0 = f2bf(v0), h1 = f2bf(v1);
    unsigned short l0 = f2bf(v0 - bf2f(h0)), l1 = f2bf(v1 - bf2f(h1));
    size_t off = (size_t)(n0 + row) * 1024 + t2;
    *(unsigned int*)&base[off] = (unsigned int)h0 | ((unsigned int)h1 << 16);
    *(unsigned int*)&base[off + PLX] = (unsigned int)l0 | ((unsigned int)l1 << 16);
  }
}

// ---------------- generic fp32 tiled GEMM (64x64 tile) + pair batching ----------------
// LOWER: linearized lower-triangular tile grid (m0 >= n0) for symmetric outputs.
template<bool TA, bool TB, bool ACC, bool RELU, bool SYRK = false, bool LOWER = false>
__global__ __launch_bounds__(256) void gemm_k(
    const float* __restrict__ A, const float* __restrict__ B,
    const float* __restrict__ bias, float* __restrict__ C,
    int M, int Nc, int K, int lda, int ldb, int ldc,
    long long sA, long long sB, long long sC, float alpha,
    int pairs, long long pA, long long pB, long long pC) {
  __shared__ float As[16][68];
  __shared__ float Bs[16][68];
  const int bz = blockIdx.z;
  const int b = bz / pairs;
  const int p = bz - b * pairs;
  A += (size_t)b * sA + (size_t)p * pA;
  B += (size_t)b * sB + (size_t)p * pB;
  C += (size_t)b * sC + (size_t)p * pC;
  int n0, m0;
  if (LOWER) {
    int t = blockIdx.x, bi = 0;
    while (t > bi) { t -= bi + 1; ++bi; }
    m0 = bi * 64; n0 = t * 64;
  } else {
    n0 = blockIdx.x * 64;
    m0 = blockIdx.y * 64;
  }
  const int tid = threadIdx.x;
  const int tn = (tid & 15) * 4;
  const int tm = (tid >> 4) * 4;
  float acc[4][4];
#pragma unroll
  for (int i = 0; i < 4; ++i)
#pragma unroll
    for (int j = 0; j < 4; ++j) acc[i][j] = 0.f;

  const int kbeg = SYRK ? (m0 > n0 ? m0 : n0) : 0;
  for (int k0 = kbeg; k0 < K; k0 += 16) {
    if (TA) {
      const int lk = tid >> 4;
      const int lm = (tid & 15) * 4;
      const float4 v = *(const float4*)&A[(size_t)(k0 + lk) * lda + m0 + lm];
      *(float4*)&As[lk][lm] = v;
    } else {
      const int lm = tid >> 2;
      const int lk = (tid & 3) * 4;
      const float4 v = *(const float4*)&A[(size_t)(m0 + lm) * lda + k0 + lk];
      As[lk + 0][lm] = v.x; As[lk + 1][lm] = v.y; As[lk + 2][lm] = v.z; As[lk + 3][lm] = v.w;
    }
    if (TB) {
      const int ln = tid >> 2;
      const int lk = (tid & 3) * 4;
      const float4 v = *(const float4*)&B[(size_t)(n0 + ln) * ldb + k0 + lk];
      Bs[lk + 0][ln] = v.x; Bs[lk + 1][ln] = v.y; Bs[lk + 2][ln] = v.z; Bs[lk + 3][ln] = v.w;
    } else {
      const int lk = tid >> 4;
      const int ln = (tid & 15) * 4;
      const float4 v = *(const float4*)&B[(size_t)(k0 + lk) * ldb + n0 + ln];
      *(float4*)&Bs[lk][ln] = v;
    }
    __syncthreads();
#pragma unroll
    for (int kk = 0; kk < 16; ++kk) {
      const float4 a4 = *(const float4*)&As[kk][tm];
      const float4 b4 = *(const float4*)&Bs[kk][tn];
      const float av[4] = {a4.x, a4.y, a4.z, a4.w};
      const float bv[4] = {b4.x, b4.y, b4.z, b4.w};
#pragma unroll
      for (int i = 0; i < 4; ++i)
#pragma unroll
        for (int j = 0; j < 4; ++j) acc[i][j] = fmaf(av[i], bv[j], acc[i][j]);
    }
    __syncthreads();
  }
  float4 bb = make_float4(0.f, 0.f, 0.f, 0.f);
  if (bias) bb = *(const float4*)&bias[n0 + tn];
#pragma unroll
  for (int i = 0; i < 4; ++i) {
    size_t off = (size_t)(m0 + tm + i) * ldc + (n0 + tn);
    float4 v;
    v.x = alpha * acc[i][0] + bb.x;
    v.y = alpha * acc[i][1] + bb.y;
    v.z = alpha * acc[i][2] + bb.z;
    v.w = alpha * acc[i][3] + bb.w;
    if (ACC) {
      const float4 c0 = *(const float4*)&C[off];
      v.x += c0.x; v.y += c0.y; v.z += c0.z; v.w += c0.w;
    }
    if (RELU) {
      v.x = fmaxf(v.x, 0.f); v.y = fmaxf(v.y, 0.f);
      v.z = fmaxf(v.z, 0.f); v.w = fmaxf(v.w, 0.f);
    }
    *(float4*)&C[off] = v;
  }
}

// ---------------- bf16-split MFMA GEMM (128M x 128N tile, wave 64x64, K-step 32) ----------------
template<bool OUTF32, bool RELU, bool BIASROW, bool TRI = false>
__global__ __launch_bounds__(256, 2) void gemm_mfma(
    const unsigned short* __restrict__ A, const unsigned short* __restrict__ B,
    const float* __restrict__ bias, void* __restrict__ Cv,
    int K, int lda, int ldb, int ldc,
    long long sA, long long sB, long long sC,
    long long plA, long long plB, long long plC, float alpha) {
  __shared__ __align__(16) unsigned short As[2][2][128][32];   // [buf][plane][row][k]
  __shared__ __align__(16) unsigned short Bs[2][2][128][32];
  const int bz = blockIdx.z;
  A += (size_t)bz * sA;
  B += (size_t)bz * sB;
  int n0, m0;
  if (TRI) {
    int t = blockIdx.x, ti = 0;
    while (t >= 4 - ti) { t -= 4 - ti; ++ti; }
    m0 = ti * 128;
    n0 = (ti + t) * 128;
  } else {
    n0 = blockIdx.x * 128;
    m0 = blockIdx.y * 128;
  }
  const int tid = threadIdx.x;
  const int wave = tid >> 6, lane = tid & 63;
  const int wm = wave & 1, wn = wave >> 1;
  const int l15 = lane & 15, quad = lane >> 4;

  const int rl = lane >> 2;               // row within a 16-row group
  const int sl = lane & 3;                // 16B slot within the 64B row
  const int qsw = sl ^ ((rl >> 1) & 3);   // global k-quad feeding this slot
  const unsigned short* gsrc;
  unsigned short* lbase;
  int ldx, row0;
  if (wave < 2) { gsrc = A + (wave ? plA : 0); lbase = &As[0][wave][0][0]; ldx = lda; row0 = m0; }
  else          { gsrc = B + (wave == 3 ? plB : 0); lbase = &Bs[0][wave - 2][0][0]; ldx = ldb; row0 = n0; }
  const unsigned short* gbase = gsrc + (size_t)(row0 + rl) * ldx + qsw * 8;
  const int rq = (quad ^ ((l15 >> 1) & 3)) * 8;

  f32x4 acc[4][4];
#pragma unroll
  for (int i = 0; i < 4; ++i)
#pragma unroll
    for (int j = 0; j < 4; ++j) acc[i][j] = (f32x4){0.f, 0.f, 0.f, 0.f};

  auto STAGE = [&](int buf, int kt) {
    const unsigned short* gk = gbase + (kt << 5);
    unsigned short* ld = lbase + buf * 8192;
#pragma unroll
    for (int t = 0; t < 8; ++t)
      gl_lds16(gk + (size_t)(t * 16) * ldx, ld + t * 512);
  };
  auto COMPUTE = [&](int buf) {
    bf16x8 ah[4], al[4], bh[4], bl[4];
#pragma unroll
    for (int i = 0; i < 4; ++i) {
      int m_l = wm * 64 + i * 16 + l15;
      int n_l = wn * 64 + i * 16 + l15;
      ah[i] = *(const bf16x8*)&As[buf][0][m_l][rq];
      al[i] = *(const bf16x8*)&As[buf][1][m_l][rq];
      bh[i] = *(const bf16x8*)&Bs[buf][0][n_l][rq];
      bl[i] = *(const bf16x8*)&Bs[buf][1][n_l][rq];
    }
    __builtin_amdgcn_s_setprio(1);
#pragma unroll
    for (int i = 0; i < 4; ++i)
#pragma unroll
      for (int j = 0; j < 4; ++j) {
        acc[i][j] = __builtin_amdgcn_mfma_f32_16x16x32_bf16(ah[i], bh[j], acc[i][j], 0, 0, 0);
        acc[i][j] = __builtin_amdgcn_mfma_f32_16x16x32_bf16(ah[i], bl[j], acc[i][j], 0, 0, 0);
        acc[i][j] = __builtin_amdgcn_mfma_f32_16x16x32_bf16(al[i], bh[j], acc[i][j], 0, 0, 0);
      }
    __builtin_amdgcn_s_setprio(0);
  };

  const int NT = K >> 5;   // even at every call site
  STAGE(0, 0);
  for (int t = 0; t < NT; t += 2) {
    STAGE(1, t + 1);
    asm volatile("s_waitcnt vmcnt(8)" ::: "memory");
    __builtin_amdgcn_sched_barrier(0);
    __builtin_amdgcn_s_barrier();
    COMPUTE(0);
    __builtin_amdgcn_s_barrier();
    if (t + 2 < NT) {
      STAGE(0, t + 2);
      asm volatile("s_waitcnt vmcnt(8)" ::: "memory");
    } else {
      asm volatile("s_waitcnt vmcnt(0)" ::: "memory");
    }
    __builtin_amdgcn_sched_barrier(0);
    __builtin_amdgcn_s_barrier();
    COMPUTE(1);
    __builtin_amdgcn_s_barrier();
  }
#pragma unroll
  for (int i = 0; i < 4; ++i)
#pragma unroll
    for (int j = 0; j < 4; ++j)
#pragma unroll
      for (int r = 0; r < 4; ++r) {
        int m_g = m0 + wm * 64 + i * 16 + quad * 4 + r;
        int n_g = n0 + wn * 64 + j * 16 + l15;
        float v = alpha * acc[i][j][r];
        if (BIASROW) v += bias[m_g];
        if (RELU) v = fmaxf(v, 0.f);
        if (OUTF32) {
          float* C = (float*)Cv + (size_t)bz * sC;
          C[(size_t)m_g * ldc + n_g] = v;
        } else {
          unsigned short* C = (unsigned short*)Cv + (size_t)bz * sC;
          unsigned short h = f2bf(v);
          C[(size_t)m_g * ldc + n_g] = h;
          C[(size_t)m_g * ldc + n_g + plC] = f2bf(v - bf2f(h));
        }
      }
}

// ---------------- weight pack: W (K x N f32) -> Wt (N x K bf16 hi/lo) ----------------
__global__ __launch_bounds__(256) void wpack_k(const float* __restrict__ W, unsigned short* __restrict__ Wt,
                                               int K, int N, long long plane) {
  __shared__ float t[64][65];
  int k0 = blockIdx.x * 64, n0 = blockIdx.y * 64;
  for (int idx = threadIdx.x; idx < 4096; idx += 256) {
    int r = idx >> 6, c = idx & 63;
    t[r][c] = W[(size_t)(k0 + r) * N + n0 + c];
  }
  __syncthreads();
  for (int idx = threadIdx.x; idx < 4096; idx += 256) {
    int r = idx >> 6, c = idx & 63;
    float v = t[c][r];
    unsigned short h = f2bf(v);
    size_t off = (size_t)(n0 + r) * K + k0 + c;
    Wt[off] = h;
    Wt[off + plane] = f2bf(v - bf2f(h));
  }
}

// ---------------- batched transpose-pack: Wtri (b,k,n f32) -> Wp (b,n,k bf16 hi/lo) ----------------
__global__ __launch_bounds__(256) void wpackb_k(const float* __restrict__ W, unsigned short* __restrict__ Wt) {
  __shared__ float t[64][65];
  int b = blockIdx.z;
  int k0 = blockIdx.x * 64, n0 = blockIdx.y * 64;
  const float* Wb = W + (size_t)b * PB;
  unsigned short* Wtb = Wt + (size_t)b * PB;
  for (int idx = threadIdx.x; idx < 4096; idx += 256) {
    int r = idx >> 6, c = idx & 63;
    t[r][c] = Wb[(size_t)(k0 + r) * CN + n0 + c];
  }
  __syncthreads();
  for (int idx = threadIdx.x; idx < 4096; idx += 256) {
    int r = idx >> 6, c = idx & 63;
    float v = t[c][r];
    unsigned short h = f2bf(v);
    size_t off = (size_t)(n0 + r) * CN + k0 + c;
    Wtb[off] = h;
    Wtb[off + (size_t)CB * PB] = f2bf(v - bf2f(h));
  }
}

// ---------------- std vectors ----------------
__global__ void sds_k(const float* __restrict__ covx, const float* __restrict__ covr,
                      float* __restrict__ sdx, float* __restrict__ sdr) {
  int idx = blockIdx.x * 256 + threadIdx.x;
  int b = idx >> 9, i = idx & (CN - 1);
  size_t off = (size_t)b * PB + (size_t)i * (CN + 1);
  sdx[idx] = sqrtf(fmaxf(covx[off], EPSF));
  sdr[idx] = sqrtf(fmaxf(covr[off], EPSF));
}

// tile-pair prep with mirror
__global__ __launch_bounds__(256) void prep_mirror(float* __restrict__ covx, float* __restrict__ covr,
                                                   const float* __restrict__ sdx, const float* __restrict__ sdr,
                                                   float* __restrict__ Lm, float* __restrict__ Wtri) {
  int b = blockIdx.y;
  int p = blockIdx.x, ti = 0;
  while (p >= 8 - ti) { p -= 8 - ti; ++ti; }
  int tj = ti + p;
  __shared__ float tx[64][65], tr2[64][65], tl[64][65];
  int row = threadIdx.x >> 2;
  int c0 = (threadIdx.x & 3) * 16;
  size_t src = (size_t)b * PB + (size_t)(ti * 64 + row) * CN + tj * 64;
  float sdi = sdx[b * CN + ti * 64 + row];
  float sri = sdr[b * CN + ti * 64 + row];
  int gi = ti * 64 + row;
  const float4 zz = make_float4(0.f, 0.f, 0.f, 0.f);
#pragma unroll
  for (int q = 0; q < 4; ++q) {
    int c = c0 + q * 4;
    float4 cx = *(const float4*)&covx[src + c];
    float4 cr = *(const float4*)&covr[src + c];
    float4 ox, orr, ol;
#pragma unroll
    for (int e = 0; e < 4; ++e) {
      int gj = tj * 64 + c + e;
      float cxe = (&cx.x)[e], cre = (&cr.x)[e];
      bool diag = (gi == gj);
      float vx = diag ? 1.0f : cxe / (sdi * sdx[b * CN + gj]);
      float vr = diag ? 1.0f : cre / (sri * sdr[b * CN + gj]);
      float vl = cxe + (diag ? 0.001f : 0.0f);
      (&ox.x)[e] = vx; (&orr.x)[e] = vr; (&ol.x)[e] = vl;
      tx[row][c + e] = vx; tr2[row][c + e] = vr; tl[row][c + e] = vl;
    }
    *(float4*)&covx[src + c] = ox;
    *(float4*)&covr[src + c] = orr;
    *(float4*)&Lm[src + c] = ol;
    *(float4*)&Wtri[src + c] = zz;
  }
  if (ti != tj) {
    __syncthreads();
    size_t dst = (size_t)b * PB + (size_t)(tj * 64 + row) * CN + ti * 64;
#pragma unroll
    for (int q = 0; q < 4; ++q) {
      int c = c0 + q * 4;
      float4 ox, orr, ol;
#pragma unroll
      for (int e = 0; e < 4; ++e) {
        (&ox.x)[e] = tx[c + e][row];
        (&orr.x)[e] = tr2[c + e][row];
        (&ol.x)[e] = tl[c + e][row];
      }
      *(float4*)&covx[dst + c] = ox;
      *(float4*)&covr[dst + c] = orr;
      *(float4*)&Lm[dst + c] = ol;
      *(float4*)&Wtri[dst + c] = zz;
    }
  }
}

// ---------------- wave-level 64x64 SPD chol + scaled inverse (lane = column) ----------------
// Lane c holds column c of A in a[0..63]. No LDS, no barriers: pivot columns broadcast
// via v_readlane (fully unrolled -> compile-time register indices & lane immediates).
// Same LDL math as the verified barrier version: deferred scaling, unit-lower inverse
// by forward substitution, rows scaled by 1/sqrt(d_r). Output in v[]: column c of
// W = chol(A)^{-1} (lower; v[r] = 0 for r < c).
__device__ __forceinline__ void chol_inv64_wave(float a[64], float v[64], int lane) {
  // factorization: column c frozen at step c (f = 0 for lane <= i)
#pragma unroll
  for (int i = 0; i < 64; ++i) {
    float dinv = 1.0f / rdlane(a[i], i);
    float f = (lane > i) ? a[i] * dinv : 0.0f;   // A'[i][c]/d_i (symmetry: = A'[c][i]/d_i)
#pragma unroll
    for (int r = i + 1; r < 64; ++r)
      a[r] = fmaf(-f, rdlane(a[r], i), a[r]);
  }
  // forward substitution: M v = e_c, M unit lower with M[r][k] = a_k[r]/d_k
#pragma unroll
  for (int r = 0; r < 64; ++r) v[r] = (r == lane) ? 1.0f : 0.0f;
#pragma unroll
  for (int k = 0; k < 64; ++k) {
    float g = v[k] * (1.0f / rdlane(a[k], k));
#pragma unroll
    for (int r = k + 1; r < 64; ++r)
      v[r] = fmaf(-rdlane(a[r], k), g, v[r]);
  }
  // scale rows by 1/sqrt(d_r); zero above diagonal
#pragma unroll
  for (int r = 0; r < 64; ++r) {
    float dr = sqrtf(rdlane(a[r], r));
    v[r] = (r >= lane) ? v[r] / dr : 0.0f;
  }
}

// ---------------- 128x128 diag block: chol + full inverse W128 = L128^{-1} ----------------
// W128 = [[W11, 0], [W21, W22]]; wave 0 runs the serial 64-chols barrier-free
// (chol_inv64_wave); all 4 waves run the LDS matmuls (L21, A22', T, W21).
__global__ __launch_bounds__(256) void chol_diag128(const float* __restrict__ A,
                                                    float* __restrict__ Winv, int kstep) {
  int b = blockIdx.x;
  const float* Ab = A + (size_t)b * PB + (size_t)(kstep * 128) * CN + kstep * 128;
  float* Wb = Winv + (size_t)b * 65536 + (size_t)kstep * 16384;
  const int tid = threadIdx.x;
  const int lane = tid & 63;
  const int wv = tid >> 6;
  const int r = tid >> 2, s = tid & 3, c0 = s * 16;
  __shared__ float W11s[64][65], L21s[64][65], W22s[64][65], Ts[64][65];
  float a[64], v[64];

  // ---- A11 -> W11 (wave 0 only; barrier-free) ----
  if (wv == 0) {
#pragma unroll
    for (int q = 0; q < 64; ++q) a[q] = Ab[(size_t)q * CN + lane];   // coalesced per q
    chol_inv64_wave(a, v, lane);
#pragma unroll
    for (int q = 0; q < 64; ++q) {
      W11s[q][lane] = v[q];
      Wb[(size_t)q * 128 + lane] = v[q];
      Wb[(size_t)q * 128 + 64 + lane] = 0.f;     // zero top-right block
    }
  }
  // stage A21 into Ts (all waves, (r,c0) mapping)
#pragma unroll
  for (int q = 0; q < 4; ++q) {
    float4 t4 = *(const float4*)&Ab[(size_t)(64 + r) * CN + c0 + q * 4];
    Ts[r][c0+q*4+0]=t4.x; Ts[r][c0+q*4+1]=t4.y; Ts[r][c0+q*4+2]=t4.z; Ts[r][c0+q*4+3]=t4.w;
  }
  __syncthreads();                               // B1: W11s + Ts(A21) ready
  // ---- L21 = A21 * W11^T ----
  float l21[16];
#pragma unroll
  for (int cc = 0; cc < 16; ++cc) l21[cc] = 0.f;
  for (int k = 0; k < 64; ++k) {
    float t = Ts[r][k];
#pragma unroll
    for (int cc = 0; cc < 16; ++cc) l21[cc] = fmaf(t, W11s[c0 + cc][k], l21[cc]);
  }
#pragma unroll
  for (int cc = 0; cc < 16; ++cc) L21s[r][c0 + cc] = l21[cc];
  __syncthreads();                               // B2: L21s ready, Ts(A21) reads done
  // ---- A22' = A22 - L21 L21^T -> stage into Ts ----
  float a16[16];
#pragma unroll
  for (int q = 0; q < 4; ++q) {
    float4 t4 = *(const float4*)&Ab[(size_t)(64 + r) * CN + 64 + c0 + q * 4];
    a16[q*4+0]=t4.x; a16[q*4+1]=t4.y; a16[q*4+2]=t4.z; a16[q*4+3]=t4.w;
  }
  for (int k = 0; k < 64; ++k) {
    float t = L21s[r][k];
#pragma unroll
    for (int cc = 0; cc < 16; ++cc) a16[cc] = fmaf(-t, L21s[c0 + cc][k], a16[cc]);
  }
#pragma unroll
  for (int cc = 0; cc < 16; ++cc) Ts[r][c0 + cc] = a16[cc];
  __syncthreads();                               // B3: Ts(A22') ready
  // ---- A22' -> W22 (wave 0 only) ----
  if (wv == 0) {
#pragma unroll
    for (int q = 0; q < 64; ++q) a[q] = Ts[q][lane];                 // conflict-free cols
    chol_inv64_wave(a, v, lane);
#pragma unroll
    for (int q = 0; q < 64; ++q) {
      W22s[q][lane] = v[q];
      Wb[(size_t)(64 + q) * 128 + 64 + lane] = v[q];
    }
  }
  __syncthreads();                               // B4: W22s ready, Ts(A22') reads done
  // ---- T = L21 * W11 -> Ts ----
  float t16[16];
#pragma unroll
  for (int cc = 0; cc < 16; ++cc) t16[cc] = 0.f;
  for (int k = 0; k < 64; ++k) {
    float t = L21s[r][k];
#pragma unroll
    for (int cc = 0; cc < 16; ++cc) t16[cc] = fmaf(t, W11s[k][c0 + cc], t16[cc]);
  }
#pragma unroll
  for (int cc = 0; cc < 16; ++cc) Ts[r][c0 + cc] = t16[cc];
  __syncthreads();                               // B5: Ts(T) ready
  // ---- W21 = -W22 * T ----
  float w21[16];
#pragma unroll
  for (int cc = 0; cc < 16; ++cc) w21[cc] = 0.f;
  for (int k = 0; k < 64; ++k) {
    float t = W22s[r][k];
#pragma unroll
    for (int cc = 0; cc < 16; ++cc) w21[cc] = fmaf(t, Ts[k][c0 + cc], w21[cc]);
  }
#pragma unroll
  for (int q = 0; q < 4; ++q) {
    float4 o = make_float4(-w21[q*4+0], -w21[q*4+1], -w21[q*4+2], -w21[q*4+3]);
    *(float4*)&Wb[(size_t)(64 + r) * 128 + c0 + q * 4] = o;
  }
}

// ---------------- panel update: Apan(Mt x 128) = Apan * W128^T, in place ----------------
__global__ __launch_bounds__(256) void gemm_panel(float* __restrict__ A, const float* __restrict__ W) {
  int b = blockIdx.y;
  float* Ab = A + (size_t)b * PB;
  const float* Wb = W + (size_t)b * 65536;
  const int m0 = blockIdx.x * 64;
  const int tid = threadIdx.x;
  const int lane = tid & 63, w = tid >> 6;
  const int tm = w * 16 + (lane >> 4) * 4;
  const int tn = (lane & 15) * 8;
  __shared__ float As[16][68];
  __shared__ float Bs[16][136];
  float acc[4][8];
#pragma unroll
  for (int i = 0; i < 4; ++i)
#pragma unroll
    for (int j = 0; j < 8; ++j) acc[i][j] = 0.f;
  for (int k0 = 0; k0 < 128; k0 += 16) {
    {
      int lm = tid >> 2, lkq = tid & 3;
      float4 v4 = *(const float4*)&Ab[(size_t)(m0 + lm) * CN + k0 + lkq * 4];
      As[lkq*4+0][lm] = v4.x; As[lkq*4+1][lm] = v4.y; As[lkq*4+2][lm] = v4.z; As[lkq*4+3][lm] = v4.w;
    }
#pragma unroll
    for (int h = 0; h < 2; ++h) {
      int idx2 = tid + h * 256;
      int cc = idx2 >> 2, kq = idx2 & 3;
      float4 v4 = *(const float4*)&Wb[(size_t)cc * 128 + k0 + kq * 4];
      Bs[kq*4+0][cc] = v4.x; Bs[kq*4+1][cc] = v4.y; Bs[kq*4+2][cc] = v4.z; Bs[kq*4+3][cc] = v4.w;
    }
    __syncthreads();
#pragma unroll
    for (int kk = 0; kk < 16; ++kk) {
      float a0 = As[kk][tm], a1 = As[kk][tm+1], a2 = As[kk][tm+2], a3 = As[kk][tm+3];
      float b8[8];
#pragma unroll
      for (int j = 0; j < 8; ++j) b8[j] = Bs[kk][tn + j];
#pragma unroll
      for (int j = 0; j < 8; ++j) {
        acc[0][j] = fmaf(a0, b8[j], acc[0][j]);
        acc[1][j] = fmaf(a1, b8[j], acc[1][j]);
        acc[2][j] = fmaf(a2, b8[j], acc[2][j]);
        acc[3][j] = fmaf(a3, b8[j], acc[3][j]);
      }
    }
    __syncthreads();
  }
#pragma unroll
  for (int i = 0; i < 4; ++i) {
    float4 o0 = make_float4(acc[i][0], acc[i][1], acc[i][2], acc[i][3]);
    float4 o1 = make_float4(acc[i][4], acc[i][5], acc[i][6], acc[i][7]);
    *(float4*)&Ab[(size_t)(m0 + tm + i) * CN + tn] = o0;
    *(float4*)&Ab[(size_t)(m0 + tm + i) * CN + tn + 4] = o1;
  }
}

// scatter 128x128 W blocks onto the Wtri diagonal
__global__ void wdiag128_k(const float* __restrict__ Winv, float* __restrict__ W) {
  int e = blockIdx.x * 256 + threadIdx.x;   // CB * 65536 total
  int b = e >> 16;
  int r2 = e & 65535;
  int blk = r2 >> 14;
  int idx = r2 & 16383;
  int row = idx >> 7, col = idx & 127;
  W[(size_t)b * PB + (size_t)(blk * 128 + row) * CN + blk * 128 + col] = Winv[e];
}

__global__ void sdp_k(const float* __restrict__ prec, float* __restrict__ sdp) {
  int idx = blockIdx.x * 256 + threadIdx.x;
  int b = idx >> 9, i = idx & (CN - 1);
  sdp[idx] = sqrtf(fmaxf(prec[(size_t)b * PB + (size_t)i * (CN + 1)], EPSF));
}

// tile-pair partial-corr with mirror + fused similarity sums
__global__ __launch_bounds__(256) void pc_fuse(float* __restrict__ prec, const float* __restrict__ sdp,
                                               const float* __restrict__ covx, const float* __restrict__ covr,
                                               float* __restrict__ sums) {
  int b = blockIdx.y;
  int p = blockIdx.x, ti = 0;
  while (p >= 8 - ti) { p -= 8 - ti; ++ti; }
  int tj = ti + p;
  __shared__ float tp[64][65];
  int row = threadIdx.x >> 2;
  int c0 = (threadIdx.x & 3) * 16;
  size_t src = (size_t)b * PB + (size_t)(ti * 64 + row) * CN + tj * 64;
  float si = sdp[b * CN + ti * 64 + row];
  int gi = ti * 64 + row;
  float pp = 0.f, ss = 0.f, cc = 0.f, ps = 0.f, pcv = 0.f, sc = 0.f;
#pragma unroll
  for (int q = 0; q < 4; ++q) {
    int c = c0 + q * 4;
    float4 pv = *(const float4*)&prec[src + c];
    float4 px = *(const float4*)&covx[src + c];
    float4 pr = *(const float4*)&covr[src + c];
    float4 ov;
#pragma unroll
    for (int e = 0; e < 4; ++e) {
      int gj = tj * 64 + c + e;
      float arg = (gi == gj) ? 1.0f : -(&pv.x)[e] / (si * sdp[b * CN + gj]);
      float v = tanhf(arg);
      (&ov.x)[e] = v;
      tp[row][c + e] = v;
      if (gj > gi) {
        float P = (&px.x)[e], S = (&pr.x)[e];
        pp += P * P; ss += S * S; cc += v * v;
        ps += P * S; pcv += P * v; sc += S * v;
      }
    }
    *(float4*)&prec[src + c] = ov;
  }
  if (ti != tj) {
    __syncthreads();
    size_t dst = (size_t)b * PB + (size_t)(tj * 64 + row) * CN + ti * 64;
#pragma unroll
    for (int q = 0; q < 4; ++q) {
      int c = c0 + q * 4;
      float4 ov;
#pragma unroll
      for (int e = 0; e < 4; ++e) (&ov.x)[e] = tp[c + e][row];
      *(float4*)&prec[dst + c] = ov;
    }
  }
#pragma unroll
  for (int m = 1; m < 64; m <<= 1) {
    pp += __shfl_xor(pp, m, 64);
    ss += __shfl_xor(ss, m, 64);
    cc += __shfl_xor(cc, m, 64);
    ps += __shfl_xor(ps, m, 64);
    pcv += __shfl_xor(pcv, m, 64);
    sc += __shfl_xor(sc, m, 64);
  }
  if ((threadIdx.x & 63) == 0) {
    atomicAdd(&sums[b * 6 + 0], pp);
    atomicAdd(&sums[b * 6 + 1], ss);
    atomicAdd(&sums[b * 6 + 2], cc);
    atomicAdd(&sums[b * 6 + 3], ps);
    atomicAdd(&sums[b * 6 + 4], pcv);
    atomicAdd(&sums[b * 6 + 5], sc);
  }
}

__global__ void alphas_k(const float* __restrict__ sums, const float* __restrict__ gamma,
                         float* __restrict__ alph) {
  int b = threadIdx.x;
  if (b >= CB) return;
  float sPP = sums[b * 6 + 0], sSS = sums[b * 6 + 1], sCC = sums[b * 6 + 2];
  float sPS = sums[b * 6 + 3], sPC = sums[b * 6 + 4], sSC = sums[b * 6 + 5];
  float numP = 0.5f * (sPS + sPC), numS = 0.5f * (sPS + sSC), numC = 0.5f * (sPC + sSC);
  float noP = 0.5f * sqrtf(sSS + sCC + 2.f * sSC);
  float noS = 0.5f * sqrtf(sPP + sCC + 2.f * sPC);
  float noC = 0.5f * sqrtf(sPP + sSS + 2.f * sPS);
  float dP = fmaxf(sqrtf(sPP), EPSF) * fmaxf(noP, EPSF);
  float dS = fmaxf(sqrtf(sSS), EPSF) * fmaxf(noS, EPSF);
  float dC = fmaxf(sqrtf(sCC), EPSF) * fmaxf(noC, EPSF);
  float g = gamma[0];
  float aP = g * numP / dP, aS = g * numS / dS, aC = g * numC / dC;
  float m = fmaxf(fmaxf(aP, aS), aC);
  float eP = expf(aP - m), eS = expf(aS - m), eC = expf(aC - m);
  float inv = 1.f / (eP + eS + eC);
  alph[b * 3 + 0] = eP * inv;
  alph[b * 3 + 1] = eS * inv;
  alph[b * 3 + 2] = eC * inv;
}

// ---------------- fused: A_fused row + rowsum + LayerNorm features + bf16 pack ----------------
__global__ __launch_bounds__(256) void bfxb_k(const float* __restrict__ Pm, const float* __restrict__ Sm,
                                              const float* __restrict__ Cm, const float* __restrict__ alph,
                                              const float* __restrict__ lng, const float* __restrict__ lnb,
                                              float* __restrict__ Af, float* __restrict__ dinv,
                                              unsigned short* __restrict__ Xpk) {
  int b = blockIdx.y, n = blockIdx.x;
  int tid = threadIdx.x;
  size_t base = (size_t)b * PB + (size_t)n * CN;
  float v[6];
  v[0] = Pm[base + tid];
  v[1] = Pm[base + 256 + tid];
  v[2] = Sm[base + tid];
  v[3] = Sm[base + 256 + tid];
  v[4] = Cm[base + tid];
  v[5] = Cm[base + 256 + tid];
  float ls = 0.f, lq = 0.f;
#pragma unroll
  for (int k = 0; k < 6; ++k) { ls += v[k]; lq += v[k] * v[k]; }
  float aP = alph[b * 3 + 0], aS = alph[b * 3 + 1], aC = alph[b * 3 + 2];
  float af0 = (n == tid) ? 1.0f : aP * v[0] + aS * v[2] + aC * v[4];
  float af1 = (n == 256 + tid) ? 1.0f : aP * v[1] + aS * v[3] + aC * v[5];
  Af[base + tid] = af0;
  Af[base + 256 + tid] = af1;
  float vsum = af0 + af1;
#pragma unroll
  for (int m = 1; m < 64; m <<= 1) {
    ls += __shfl_xor(ls, m, 64);
    lq += __shfl_xor(lq, m, 64);
    vsum += __shfl_xor(vsum, m, 64);
  }
  __shared__ float wls[4], wlq[4], wvs[4];
  int w = tid >> 6;
  if ((tid & 63) == 0) { wls[w] = ls; wlq[w] = lq; wvs[w] = vsum; }
  __syncthreads();
  float tls = wls[0] + wls[1] + wls[2] + wls[3];
  float tlq = wlq[0] + wlq[1] + wlq[2] + wlq[3];
  float tvs = wvs[0] + wvs[1] + wvs[2] + wvs[3];
  if (tid == 0) dinv[b * CN + n] = 1.0f / sqrtf(fmaxf(tvs, EPSF));
  float mu = tls * (1.0f / CIN);
  float var = tlq * (1.0f / CIN) - mu * mu;
  float rstd = 1.0f / sqrtf(var + 1e-5f);
  const size_t XPLANE = (size_t)CB * CN * CIN;
  unsigned short* Xrow = Xpk + ((size_t)b * CN + n) * CIN;
#pragma unroll
  for (int k = 0; k < 6; ++k) {
    int pos = k * 256 + tid;
    float o = (v[k] - mu) * rstd * lng[pos] + lnb[pos];
    unsigned short h = f2bf(o);
    Xrow[pos] = h;
    Xrow[pos + XPLANE] = f2bf(o - bf2f(h));
  }
}

// normalize + pack to bf16 hi/lo planes
__global__ __launch_bounds__(256) void norm_adj_k(const float* __restrict__ AfF, const float* __restrict__ dinv,
                                                  unsigned short* __restrict__ Afp) {
  int b = blockIdx.y;
  int e = blockIdx.x * 256 + threadIdx.x;
  int i = e >> 9, j = e & (CN - 1);
  size_t off = (size_t)b * PB + e;
  float v = AfF[off] * dinv[b * CN + i] * dinv[b * CN + j];
  unsigned short h = f2bf(v);
  Afp[off] = h;
  Afp[off + SBNN] = f2bf(v - bf2f(h));
}

// ---------------- head: two-stage mean-pool + classifier + sigmoid ----------------
__global__ __launch_bounds__(256) void head1_k(const float* __restrict__ H, const float* __restrict__ Wc,
                                               float* __restrict__ logit) {
  int b = blockIdx.x, c = blockIdx.y;
  int d = threadIdx.x;
  const float* Hb = H + (size_t)b * CN * CD + (size_t)c * 64 * CD;
  float s0 = 0.f, s1 = 0.f;
  for (int n = 0; n < 64; ++n) {
    s0 += Hb[(size_t)n * CD + d];
    s1 += Hb[(size_t)n * CD + 256 + d];
  }
  __shared__ float red[256];
  red[d] = s0 * Wc[d] + s1 * Wc[256 + d];
  __syncthreads();
  for (int k = 128; k > 0; k >>= 1) {
    if (d < k) red[d] += red[d + k];
    __syncthreads();
  }
  if (d == 0) atomicAdd(&logit[b], red[0]);
}

__global__ void sig_k(const float* __restrict__ logit, const float* __restrict__ bc, float* __restrict__ out) {
  int b = threadIdx.x;
  if (b < CB) out[b] = 1.0f / (1.0f + expf(-(logit[b] * (1.0f / CN) + bc[0])));
}

// ---------------- launcher ----------------
extern "C" void kernel_launch(void* const* d_in, const int* in_sizes, int n_in,
                              void* d_out, int out_size, void* d_ws, size_t ws_size,
                              hipStream_t stream) {
  const float* x    = (const float*)d_in[0];
  const float* gam  = (const float*)d_in[1];
  const float* lng  = (const float*)d_in[2];
  const float* lnb  = (const float*)d_in[3];
  const float* W0   = (const float*)d_in[4];
  const float* b0   = (const float*)d_in[5];
  const float* W1   = (const float*)d_in[6];
  const float* b1   = (const float*)d_in[7];
  const float* W2   = (const float*)d_in[8];
  const float* b2   = (const float*)d_in[9];
  const float* Wc   = (const float*)d_in[10];
  const float* bc   = (const float*)d_in[11];
  float* out = (float*)d_out;
  float* ws = (float*)d_ws;

  unsigned short* Xtp = (unsigned short*)ws;
  float* Winv8 = ws;                      // 16 x 65536 floats (4 MB); Xtp slots 0-5 dead after cov
  float* Ttmp  = ws + 1048576;            // after Winv8
  float* covx  = ws + 16777216;
  float* covr  = covx + SBNN;
  float* Lm    = covx + 2 * SBNN;
  float* Wtri  = covx + 3 * SBNN;
  float* prY   = covx + 4 * SBNN;
  float* sdx   = covx + 5 * SBNN;
  float* sdr   = sdx + 8192;
  float* sdp   = sdr + 8192;
  float* dinv  = sdp + 8192;
  float* gm    = dinv + 8192;
  float* ms    = gm + 8192;
  float* sums  = ms + 8192;
  float* alph  = sums + 96;
  float* logit = alph + 48;

  unsigned short* Xpk  = (unsigned short*)ws;
  unsigned short* Afp  = (unsigned short*)(ws + 12582912);
  float*          AfF  = Lm;
  unsigned short* Wp   = (unsigned short*)Lm;   // bf16 hi/lo pack of Wtri for MFMA SYRK
  unsigned short* w0t  = (unsigned short*)Lm;
  unsigned short* w1t  = (unsigned short*)(Lm + 1048576);
  unsigned short* w2t  = (unsigned short*)(Lm + 1572864);
  unsigned short* Zt1  = (unsigned short*)prY;
  unsigned short* Zt2  = (unsigned short*)Wtri;
  unsigned short* Zt3  = (unsigned short*)prY;
  unsigned short* H1p  = (unsigned short*)covx;
  unsigned short* H2p  = (unsigned short*)covr;
  float*          Ha   = covx;

  const float covscale = (float)(1.0 / 1023.00000001);
  const long long sPB = (long long)PB;

  zero_k<<<(8352 + 255) / 256, 256, 0, stream>>>(ms, 8352);
  colmean_k<<<dim3(2, CB, 4), 256, 0, stream>>>(x, ms);
  cpack_k<<<dim3(8, 16, CB), 256, 0, stream>>>(x, ms, Xtp);
  ranks_k<<<dim3(CN / 8, CB), 512, 0, stream>>>(x, Xtp);

  // both covariances via bf16-split MFMA, triangular tile grid
  gemm_mfma<true, false, false, true><<<dim3(10, 1, 32), 256, 0, stream>>>(
      Xtp, Xtp, nullptr, covx, 1024, 1024, 1024, CN,
      524288LL, 524288LL, sPB, PLX, PLX, 0LL, covscale);
  sds_k<<<32, 256, 0, stream>>>(covx, covr, sdx, sdr);
  prep_mirror<<<dim3(36, CB), 256, 0, stream>>>(covx, covr, sdx, sdr, Lm, Wtri);

  // blocked Cholesky, NB=128: 4 diag + 3 panel + 3 trailing dispatches
  for (int k = 0; k < 4; ++k) {
    chol_diag128<<<CB, 256, 0, stream>>>(Lm, Winv8, k);
    int Mt = CN - 128 * (k + 1);
    if (Mt > 0) {
      float* Apan = Lm + (size_t)(k + 1) * 128 * CN + k * 128;
      float* Atrl = Lm + (size_t)(k + 1) * 128 * CN + (k + 1) * 128;
      gemm_panel<<<dim3(Mt / 64, CB), 256, 0, stream>>>(Apan, Winv8 + (size_t)k * 16384);
      int nb = Mt / 64;
      gemm_k<false, true, true, false, false, true><<<dim3(nb * (nb + 1) / 2, 1, CB), 256, 0, stream>>>(
          Apan, Apan, nullptr, Atrl, Mt, Mt, 128, CN, CN, CN,
          sPB, sPB, sPB, -1.0f, 1, 0, 0, 0);
    }
  }

  // W = L^{-1}: scatter 128-diag W blocks + 2 merge levels (128->256->512)
  wdiag128_k<<<4096, 256, 0, stream>>>(Winv8, Wtri);
  gemm_k<false, false, false, false><<<dim3(2, 2, CB * 2), 256, 0, stream>>>(
      Lm + 128 * CN, Wtri, nullptr, Ttmp, 128, 128, 128, CN, CN, 128,
      sPB, sPB, 32768LL, 1.0f, 2, 131328LL, 131328LL, 16384LL);
  gemm_k<false, false, false, false><<<dim3(2, 2, CB * 2), 256, 0, stream>>>(
      Wtri + 128 * CN + 128, Ttmp, nullptr, Wtri + 128 * CN, 128, 128, 128, CN, 128, CN,
      sPB, 32768LL, sPB, -1.0f, 2, 131328LL, 16384LL, 131328LL);
  gemm_k<false, false, false, false><<<dim3(4, 4, CB), 256, 0, stream>>>(
      Lm + 256 * CN, Wtri, nullptr, Ttmp, 256, 256, 256, CN, CN, 256,
      sPB, sPB, 65536LL, 1.0f, 1, 0, 0, 0);
  gemm_k<false, false, false, false><<<dim3(4, 4, CB), 256, 0, stream>>>(
      Wtri + 256 * CN + 256, Ttmp, nullptr, Wtri + 256 * CN, 256, 256, 256, CN, 256, CN,
      sPB, 65536LL, sPB, -1.0f, 1, 0, 0, 0);

  // prec = W^T W via bf16-split MFMA (triangular grid; mirror + fused sums in pc_fuse)
  wpackb_k<<<dim3(8, 8, CB), 256, 0, stream>>>(Wtri, Wp);
  gemm_mfma<true, false, false, true><<<dim3(10, 1, CB), 256, 0, stream>>>(
      Wp, Wp, nullptr, prY, CN, CN, CN, CN,
      262144LL, 262144LL, sPB, 4194304LL, 4194304LL, 0LL, 1.0f);
  sdp_k<<<32, 256, 0, stream>>>(prY, sdp);
  pc_fuse<<<dim3(36, CB), 256, 0, stream>>>(prY, sdp, covx, covr, sums);

  alphas_k<<<1, 64, 0, stream>>>(sums, gam, alph);
  bfxb_k<<<dim3(CN, CB), 256, 0, stream>>>(covx, covr, prY, alph, lng, lnb, AfF, dinv, Xpk);
  norm_adj_k<<<dim3(1024, CB), 256, 0, stream>>>(AfF, dinv, Afp);

  wpack_k<<<dim3(24, 8), 256, 0, stream>>>(W0, w0t, CIN, CD, 786432LL);
  wpack_k<<<dim3(8, 8), 256, 0, stream>>>(W1, w1t, CD, CD, 262144LL);
  wpack_k<<<dim3(8, 8), 256, 0, stream>>>(W2, w2t, CD, CD, 262144LL);

  // GCN via bf16-split MFMA (128x128 tiles; orientation alternates, no transposes)
  gemm_mfma<false, false, true><<<dim3(64, 4, 1), 256, 0, stream>>>(
      w0t, Xpk, b0, Zt1, CIN, CIN, CIN, 8192, 0, 0, 0, 786432LL, 12582912LL, 4194304LL, 1.0f);
  gemm_mfma<false, true, false><<<dim3(4, 4, CB), 256, 0, stream>>>(
      Afp, Zt1, nullptr, H1p, CN, CN, 8192, CD, 262144LL, 512LL, 262144LL,
      4194304LL, 4194304LL, 4194304LL, 1.0f);
  gemm_mfma<false, false, true><<<dim3(64, 4, 1), 256, 0, stream>>>(
      w1t, H1p, b1, Zt2, CD, CD, CD, 8192, 0, 0, 0, 262144LL, 4194304LL, 4194304LL, 1.0f);
  gemm_mfma<false, true, false><<<dim3(4, 4, CB), 256, 0, stream>>>(
      Afp, Zt2, nullptr, H2p, CN, CN, 8192, CD, 262144LL, 512LL, 262144LL,
      4194304LL, 4194304LL, 4194304LL, 1.0f);
  gemm_mfma<false, false, true><<<dim3(64, 4, 1), 256, 0, stream>>>(
      w2t, H2p, b2, Zt3, CD, CD, CD, 8192, 0, 0, 0, 262144LL, 4194304LL, 4194304LL, 1.0f);
  gemm_mfma<true, true, false><<<dim3(4, 4, CB), 256, 0, stream>>>(
      Afp, Zt3, nullptr, Ha, CN, CN, 8192, CD, 262144LL, 512LL, 262144LL,
      4194304LL, 4194304LL, 0LL, 1.0f);

  head1_k<<<dim3(CB, 8), 256, 0, stream>>>(Ha, Wc, logit);
  sig_k<<<1, 64, 0, stream>>>(logit, bc, out);
}

// Round 8
// 1321.934 us; speedup vs baseline: 1.9579x; 1.9579x over previous
//
#include <hip/hip_runtime.h>
#include <math.h>

#define EPSF 1e-8f

constexpr int CB = 16;      // batch
constexpr int CT = 1024;    // time
constexpr int CN = 512;     // nodes
constexpr int CD = 512;     // hidden
constexpr int CIN = 1536;   // 3*N
constexpr int PB = CN * CN;
constexpr size_t SBTN = (size_t)CB * CT * CN;
constexpr size_t SBNN = (size_t)CB * PB;
constexpr long long PLX = 16777216LL;   // Xtp plane stride (u16 elems)

typedef __attribute__((ext_vector_type(8))) short bf16x8;
typedef __attribute__((ext_vector_type(4))) float f32x4;

__device__ inline unsigned short f2bf(float x) {   // RNE to bf16
  unsigned u = __float_as_uint(x);
  unsigned r = (u + 0x7fffu + ((u >> 16) & 1u)) >> 16;
  return (unsigned short)r;
}
__device__ inline float bf2f(unsigned short h) { return __uint_as_float(((unsigned)h) << 16); }

// async global->LDS, 16B per lane. LDS dest is wave-uniform base + lane*16.
__device__ inline void gl_lds16(const unsigned short* g, unsigned short* l) {
  __builtin_amdgcn_global_load_lds(
      (const __attribute__((address_space(1))) unsigned int*)g,
      (__attribute__((address_space(3))) unsigned int*)l, 16, 0, 0);
}

// SGPR broadcast of lane l's value (compile-time l in unrolled loops)
__device__ inline float rdlane(float v, int l) {
  return __int_as_float(__builtin_amdgcn_readlane(__float_as_int(v), l));
}

// ---------------- utility ----------------
__global__ void zero_k(float* p, int n) {
  int i = blockIdx.x * 256 + threadIdx.x;
  if (i < n) p[i] = 0.f;
}

// ---------------- column means ----------------
__global__ __launch_bounds__(256) void colmean_k(const float* __restrict__ x, float* __restrict__ ms) {
  int b = blockIdx.y;
  int n = blockIdx.x * 256 + threadIdx.x;
  int t0 = blockIdx.z * 256;
  const float* xb = x + (size_t)b * CT * CN + (size_t)t0 * CN + n;
  float s = 0.f;
  for (int t = 0; t < 256; ++t) s += xb[(size_t)t * CN];
  atomicAdd(&ms[b * CN + n], s);
}

// ---------------- centered transpose-pack: x (b,t,n) -> Xtp slot b (n,t) bf16 hi/lo ----------------
__global__ __launch_bounds__(256) void cpack_k(const float* __restrict__ x, const float* __restrict__ ms,
                                               unsigned short* __restrict__ Xtp) {
  __shared__ float t[64][65];
  int b = blockIdx.z, n0 = blockIdx.x * 64, t0 = blockIdx.y * 64;
  const float* xb = x + (size_t)b * CT * CN;
  for (int idx = threadIdx.x; idx < 4096; idx += 256) {
    int r = idx >> 6, c = idx & 63;
    t[r][c] = xb[(size_t)(t0 + r) * CN + n0 + c] - ms[b * CN + n0 + c] * (1.0f / CT);
  }
  __syncthreads();
  unsigned short* base = Xtp + (size_t)b * 524288;
  for (int idx = threadIdx.x; idx < 2048; idx += 256) {
    int nr = idx >> 5, tc = (idx & 31) * 2;
    float v0 = t[tc][nr], v1 = t[tc + 1][nr];
    unsigned short h0 = f2bf(v0), h1 = f2bf(v1);
    unsigned short l0 = f2bf(v0 - bf2f(h0)), l1 = f2bf(v1 - bf2f(h1));
    size_t off = (size_t)(n0 + nr) * 1024 + t0 + tc;
    *(unsigned int*)&base[off] = (unsigned int)h0 | ((unsigned int)h1 << 16);
    *(unsigned int*)&base[off + PLX] = (unsigned int)l0 | ((unsigned int)l1 << 16);
  }
}

// ---------------- Spearman ranks: merge-split bitonic, 1 column/wave, 8 columns/block ----------------
static __device__ inline unsigned long long shflx64(unsigned long long v, int m) {
  int lo = __shfl_xor((int)(unsigned)v, m, 64);
  int hi = __shfl_xor((int)(unsigned)(v >> 32), m, 64);
  return ((unsigned long long)(unsigned)hi << 32) | (unsigned)lo;
}

__global__ __launch_bounds__(512, 8) void ranks_k(const float* __restrict__ x, unsigned short* __restrict__ Xtp) {
  int b = blockIdx.y;
  int n0 = blockIdx.x * 8;
  __shared__ float stage[8][1032];
  const float* xb = x + (size_t)b * CT * CN + n0;
  for (int t = threadIdx.x; t < 1024; t += 512) {
    float4 v0 = *(const float4*)&xb[(size_t)t * CN];
    float4 v1 = *(const float4*)&xb[(size_t)t * CN + 4];
    stage[0][t] = v0.x; stage[1][t] = v0.y; stage[2][t] = v0.z; stage[3][t] = v0.w;
    stage[4][t] = v1.x; stage[5][t] = v1.y; stage[6][t] = v1.z; stage[7][t] = v1.w;
  }
  __syncthreads();
  const int wave = threadIdx.x >> 6;
  const int lane = threadIdx.x & 63;
  const int c = wave;
  {
    unsigned long long kv[16];
#pragma unroll
    for (int m = 0; m < 16; ++m) {
      int pos = m * 64 + lane;
      unsigned int u = __float_as_uint(stage[c][pos]);
      u = (u & 0x80000000u) ? ~u : (u | 0x80000000u);
      kv[m] = (((unsigned long long)u) << 32) | (unsigned)pos;
    }
#define CE_KV(a, bb, up) { bool sw_ = (up) ? (kv[a] > kv[bb]) : (kv[a] < kv[bb]); \
  if (sw_) { unsigned long long t_ = kv[a]; kv[a] = kv[bb]; kv[bb] = t_; } }
#pragma unroll
    for (int k2 = 2; k2 <= 16; k2 <<= 1) {
#pragma unroll
      for (int j2 = 8; j2 >= 1; j2 >>= 1) {
        if (j2 >= k2) continue;
#pragma unroll
        for (int t = 0; t < 16; ++t)
          if (!(t & j2)) { bool up2 = ((t & k2) == 0); CE_KV(t, t | j2, up2); }
      }
    }
#pragma unroll
    for (int k = 2; k <= 64; k <<= 1) {
#pragma unroll
      for (int j = 32; j >= 1; j >>= 1) {
        if (j >= k) continue;
        bool up = ((lane & k) == 0);
        bool isLow = ((lane & j) == 0);
        bool keepMin = (isLow == up);
        unsigned long long oth[16];
#pragma unroll
        for (int i = 0; i < 16; ++i) oth[i] = shflx64(kv[15 - i], j);
#pragma unroll
        for (int i = 0; i < 16; ++i) {
          unsigned long long o = oth[i];
          bool less = kv[i] < o;
          kv[i] = (less == keepMin) ? kv[i] : o;
        }
#pragma unroll
        for (int j2 = 8; j2 >= 1; j2 >>= 1)
#pragma unroll
          for (int t = 0; t < 16; ++t)
            if (!(t & j2)) CE_KV(t, t | j2, true);
      }
    }
#undef CE_KV
#pragma unroll
    for (int m = 0; m < 16; ++m) {
      unsigned int pos = (unsigned int)kv[m] & 1023u;
      stage[c][pos] = ((float)(lane * 16 + m + 1) - 512.5f) * (1.0f / 512.0f);
    }
  }
  __syncthreads();
  unsigned short* base = Xtp + (size_t)(16 + b) * 524288;
  for (int idx = threadIdx.x; idx < 4096; idx += 512) {
    int row = idx >> 9, t2 = (idx & 511) * 2;
    float v0 = stage[row][t2], v1 = stage[row][t2 + 1];
    unsigned short h0 = f2bf(v0), h1 = f2bf(v1);
    unsigned short l0 = f2bf(v0 - bf2f(h0)), l1 = f2bf(v1 - bf2f(h1));
    size_t off = (size_t)(n0 + row) * 1024 + t2;
    *(unsigned int*)&base[off] = (unsigned int)h0 | ((unsigned int)h1 << 16);
    *(unsigned int*)&base[off + PLX] = (unsigned int)l0 | ((unsigned int)l1 << 16);
  }
}

// ---------------- generic fp32 tiled GEMM (64x64 tile) + pair batching ----------------
// LOWER: linearized lower-triangular tile grid (m0 >= n0) for symmetric outputs.
template<bool TA, bool TB, bool ACC, bool RELU, bool SYRK = false, bool LOWER = false>
__global__ __launch_bounds__(256) void gemm_k(
    const float* __restrict__ A, const float* __restrict__ B,
    const float* __restrict__ bias, float* __restrict__ C,
    int M, int Nc, int K, int lda, int ldb, int ldc,
    long long sA, long long sB, long long sC, float alpha,
    int pairs, long long pA, long long pB, long long pC) {
  __shared__ float As[16][68];
  __shared__ float Bs[16][68];
  const int bz = blockIdx.z;
  const int b = bz / pairs;
  const int p = bz - b * pairs;
  A += (size_t)b * sA + (size_t)p * pA;
  B += (size_t)b * sB + (size_t)p * pB;
  C += (size_t)b * sC + (size_t)p * pC;
  int n0, m0;
  if (LOWER) {
    int t = blockIdx.x, bi = 0;
    while (t > bi) { t -= bi + 1; ++bi; }
    m0 = bi * 64; n0 = t * 64;
  } else {
    n0 = blockIdx.x * 64;
    m0 = blockIdx.y * 64;
  }
  const int tid = threadIdx.x;
  const int tn = (tid & 15) * 4;
  const int tm = (tid >> 4) * 4;
  float acc[4][4];
#pragma unroll
  for (int i = 0; i < 4; ++i)
#pragma unroll
    for (int j = 0; j < 4; ++j) acc[i][j] = 0.f;

  const int kbeg = SYRK ? (m0 > n0 ? m0 : n0) : 0;
  for (int k0 = kbeg; k0 < K; k0 += 16) {
    if (TA) {
      const int lk = tid >> 4;
      const int lm = (tid & 15) * 4;
      const float4 v = *(const float4*)&A[(size_t)(k0 + lk) * lda + m0 + lm];
      *(float4*)&As[lk][lm] = v;
    } else {
      const int lm = tid >> 2;
      const int lk = (tid & 3) * 4;
      const float4 v = *(const float4*)&A[(size_t)(m0 + lm) * lda + k0 + lk];
      As[lk + 0][lm] = v.x; As[lk + 1][lm] = v.y; As[lk + 2][lm] = v.z; As[lk + 3][lm] = v.w;
    }
    if (TB) {
      const int ln = tid >> 2;
      const int lk = (tid & 3) * 4;
      const float4 v = *(const float4*)&B[(size_t)(n0 + ln) * ldb + k0 + lk];
      Bs[lk + 0][ln] = v.x; Bs[lk + 1][ln] = v.y; Bs[lk + 2][ln] = v.z; Bs[lk + 3][ln] = v.w;
    } else {
      const int lk = tid >> 4;
      const int ln = (tid & 15) * 4;
      const float4 v = *(const float4*)&B[(size_t)(k0 + lk) * ldb + n0 + ln];
      *(float4*)&Bs[lk][ln] = v;
    }
    __syncthreads();
#pragma unroll
    for (int kk = 0; kk < 16; ++kk) {
      const float4 a4 = *(const float4*)&As[kk][tm];
      const float4 b4 = *(const float4*)&Bs[kk][tn];
      const float av[4] = {a4.x, a4.y, a4.z, a4.w};
      const float bv[4] = {b4.x, b4.y, b4.z, b4.w};
#pragma unroll
      for (int i = 0; i < 4; ++i)
#pragma unroll
        for (int j = 0; j < 4; ++j) acc[i][j] = fmaf(av[i], bv[j], acc[i][j]);
    }
    __syncthreads();
  }
  float4 bb = make_float4(0.f, 0.f, 0.f, 0.f);
  if (bias) bb = *(const float4*)&bias[n0 + tn];
#pragma unroll
  for (int i = 0; i < 4; ++i) {
    size_t off = (size_t)(m0 + tm + i) * ldc + (n0 + tn);
    float4 v;
    v.x = alpha * acc[i][0] + bb.x;
    v.y = alpha * acc[i][1] + bb.y;
    v.z = alpha * acc[i][2] + bb.z;
    v.w = alpha * acc[i][3] + bb.w;
    if (ACC) {
      const float4 c0 = *(const float4*)&C[off];
      v.x += c0.x; v.y += c0.y; v.z += c0.z; v.w += c0.w;
    }
    if (RELU) {
      v.x = fmaxf(v.x, 0.f); v.y = fmaxf(v.y, 0.f);
      v.z = fmaxf(v.z, 0.f); v.w = fmaxf(v.w, 0.f);
    }
    *(float4*)&C[off] = v;
  }
}

// ---------------- bf16-split MFMA GEMM (128M x 128N tile, wave 64x64, K-step 32) ----------------
template<bool OUTF32, bool RELU, bool BIASROW, bool TRI = false>
__global__ __launch_bounds__(256, 2) void gemm_mfma(
    const unsigned short* __restrict__ A, const unsigned short* __restrict__ B,
    const float* __restrict__ bias, void* __restrict__ Cv,
    int K, int lda, int ldb, int ldc,
    long long sA, long long sB, long long sC,
    long long plA, long long plB, long long plC, float alpha) {
  __shared__ __align__(16) unsigned short As[2][2][128][32];   // [buf][plane][row][k]
  __shared__ __align__(16) unsigned short Bs[2][2][128][32];
  const int bz = blockIdx.z;
  A += (size_t)bz * sA;
  B += (size_t)bz * sB;
  int n0, m0;
  if (TRI) {
    int t = blockIdx.x, ti = 0;
    while (t >= 4 - ti) { t -= 4 - ti; ++ti; }
    m0 = ti * 128;
    n0 = (ti + t) * 128;
  } else {
    n0 = blockIdx.x * 128;
    m0 = blockIdx.y * 128;
  }
  const int tid = threadIdx.x;
  const int wave = tid >> 6, lane = tid & 63;
  const int wm = wave & 1, wn = wave >> 1;
  const int l15 = lane & 15, quad = lane >> 4;

  const int rl = lane >> 2;               // row within a 16-row group
  const int sl = lane & 3;                // 16B slot within the 64B row
  const int qsw = sl ^ ((rl >> 1) & 3);   // global k-quad feeding this slot
  const unsigned short* gsrc;
  unsigned short* lbase;
  int ldx, row0;
  if (wave < 2) { gsrc = A + (wave ? plA : 0); lbase = &As[0][wave][0][0]; ldx = lda; row0 = m0; }
  else          { gsrc = B + (wave == 3 ? plB : 0); lbase = &Bs[0][wave - 2][0][0]; ldx = ldb; row0 = n0; }
  const unsigned short* gbase = gsrc + (size_t)(row0 + rl) * ldx + qsw * 8;
  const int rq = (quad ^ ((l15 >> 1) & 3)) * 8;

  f32x4 acc[4][4];
#pragma unroll
  for (int i = 0; i < 4; ++i)
#pragma unroll
    for (int j = 0; j < 4; ++j) acc[i][j] = (f32x4){0.f, 0.f, 0.f, 0.f};

  auto STAGE = [&](int buf, int kt) {
    const unsigned short* gk = gbase + (kt << 5);
    unsigned short* ld = lbase + buf * 8192;
#pragma unroll
    for (int t = 0; t < 8; ++t)
      gl_lds16(gk + (size_t)(t * 16) * ldx, ld + t * 512);
  };
  auto COMPUTE = [&](int buf) {
    bf16x8 ah[4], al[4], bh[4], bl[4];
#pragma unroll
    for (int i = 0; i < 4; ++i) {
      int m_l = wm * 64 + i * 16 + l15;
      int n_l = wn * 64 + i * 16 + l15;
      ah[i] = *(const bf16x8*)&As[buf][0][m_l][rq];
      al[i] = *(const bf16x8*)&As[buf][1][m_l][rq];
      bh[i] = *(const bf16x8*)&Bs[buf][0][n_l][rq];
      bl[i] = *(const bf16x8*)&Bs[buf][1][n_l][rq];
    }
    __builtin_amdgcn_s_setprio(1);
#pragma unroll
    for (int i = 0; i < 4; ++i)
#pragma unroll
      for (int j = 0; j < 4; ++j) {
        acc[i][j] = __builtin_amdgcn_mfma_f32_16x16x32_bf16(ah[i], bh[j], acc[i][j], 0, 0, 0);
        acc[i][j] = __builtin_amdgcn_mfma_f32_16x16x32_bf16(ah[i], bl[j], acc[i][j], 0, 0, 0);
        acc[i][j] = __builtin_amdgcn_mfma_f32_16x16x32_bf16(al[i], bh[j], acc[i][j], 0, 0, 0);
      }
    __builtin_amdgcn_s_setprio(0);
  };

  const int NT = K >> 5;   // even at every call site
  STAGE(0, 0);
  for (int t = 0; t < NT; t += 2) {
    STAGE(1, t + 1);
    asm volatile("s_waitcnt vmcnt(8)" ::: "memory");
    __builtin_amdgcn_sched_barrier(0);
    __builtin_amdgcn_s_barrier();
    COMPUTE(0);
    __builtin_amdgcn_s_barrier();
    if (t + 2 < NT) {
      STAGE(0, t + 2);
      asm volatile("s_waitcnt vmcnt(8)" ::: "memory");
    } else {
      asm volatile("s_waitcnt vmcnt(0)" ::: "memory");
    }
    __builtin_amdgcn_sched_barrier(0);
    __builtin_amdgcn_s_barrier();
    COMPUTE(1);
    __builtin_amdgcn_s_barrier();
  }
#pragma unroll
  for (int i = 0; i < 4; ++i)
#pragma unroll
    for (int j = 0; j < 4; ++j)
#pragma unroll
      for (int r = 0; r < 4; ++r) {
        int m_g = m0 + wm * 64 + i * 16 + quad * 4 + r;
        int n_g = n0 + wn * 64 + j * 16 + l15;
        float v = alpha * acc[i][j][r];
        if (BIASROW) v += bias[m_g];
        if (RELU) v = fmaxf(v, 0.f);
        if (OUTF32) {
          float* C = (float*)Cv + (size_t)bz * sC;
          C[(size_t)m_g * ldc + n_g] = v;
        } else {
          unsigned short* C = (unsigned short*)Cv + (size_t)bz * sC;
          unsigned short h = f2bf(v);
          C[(size_t)m_g * ldc + n_g] = h;
          C[(size_t)m_g * ldc + n_g + plC] = f2bf(v - bf2f(h));
        }
      }
}

// ---------------- weight pack: W (K x N f32) -> Wt (N x K bf16 hi/lo) ----------------
__global__ __launch_bounds__(256) void wpack_k(const float* __restrict__ W, unsigned short* __restrict__ Wt,
                                               int K, int N, long long plane) {
  __shared__ float t[64][65];
  int k0 = blockIdx.x * 64, n0 = blockIdx.y * 64;
  for (int idx = threadIdx.x; idx < 4096; idx += 256) {
    int r = idx >> 6, c = idx & 63;
    t[r][c] = W[(size_t)(k0 + r) * N + n0 + c];
  }
  __syncthreads();
  for (int idx = threadIdx.x; idx < 4096; idx += 256) {
    int r = idx >> 6, c = idx & 63;
    float v = t[c][r];
    unsigned short h = f2bf(v);
    size_t off = (size_t)(n0 + r) * K + k0 + c;
    Wt[off] = h;
    Wt[off + plane] = f2bf(v - bf2f(h));
  }
}

// ---------------- batched transpose-pack: Wtri (b,k,n f32) -> Wp (b,n,k bf16 hi/lo) ----------------
__global__ __launch_bounds__(256) void wpackb_k(const float* __restrict__ W, unsigned short* __restrict__ Wt) {
  __shared__ float t[64][65];
  int b = blockIdx.z;
  int k0 = blockIdx.x * 64, n0 = blockIdx.y * 64;
  const float* Wb = W + (size_t)b * PB;
  unsigned short* Wtb = Wt + (size_t)b * PB;
  for (int idx = threadIdx.x; idx < 4096; idx += 256) {
    int r = idx >> 6, c = idx & 63;
    t[r][c] = Wb[(size_t)(k0 + r) * CN + n0 + c];
  }
  __syncthreads();
  for (int idx = threadIdx.x; idx < 4096; idx += 256) {
    int r = idx >> 6, c = idx & 63;
    float v = t[c][r];
    unsigned short h = f2bf(v);
    size_t off = (size_t)(n0 + r) * CN + k0 + c;
    Wtb[off] = h;
    Wtb[off + (size_t)CB * PB] = f2bf(v - bf2f(h));
  }
}

// ---------------- std vectors ----------------
__global__ void sds_k(const float* __restrict__ covx, const float* __restrict__ covr,
                      float* __restrict__ sdx, float* __restrict__ sdr) {
  int idx = blockIdx.x * 256 + threadIdx.x;
  int b = idx >> 9, i = idx & (CN - 1);
  size_t off = (size_t)b * PB + (size_t)i * (CN + 1);
  sdx[idx] = sqrtf(fmaxf(covx[off], EPSF));
  sdr[idx] = sqrtf(fmaxf(covr[off], EPSF));
}

// tile-pair prep with mirror
__global__ __launch_bounds__(256) void prep_mirror(float* __restrict__ covx, float* __restrict__ covr,
                                                   const float* __restrict__ sdx, const float* __restrict__ sdr,
                                                   float* __restrict__ Lm, float* __restrict__ Wtri) {
  int b = blockIdx.y;
  int p = blockIdx.x, ti = 0;
  while (p >= 8 - ti) { p -= 8 - ti; ++ti; }
  int tj = ti + p;
  __shared__ float tx[64][65], tr2[64][65], tl[64][65];
  int row = threadIdx.x >> 2;
  int c0 = (threadIdx.x & 3) * 16;
  size_t src = (size_t)b * PB + (size_t)(ti * 64 + row) * CN + tj * 64;
  float sdi = sdx[b * CN + ti * 64 + row];
  float sri = sdr[b * CN + ti * 64 + row];
  int gi = ti * 64 + row;
  const float4 zz = make_float4(0.f, 0.f, 0.f, 0.f);
#pragma unroll
  for (int q = 0; q < 4; ++q) {
    int c = c0 + q * 4;
    float4 cx = *(const float4*)&covx[src + c];
    float4 cr = *(const float4*)&covr[src + c];
    float4 ox, orr, ol;
#pragma unroll
    for (int e = 0; e < 4; ++e) {
      int gj = tj * 64 + c + e;
      float cxe = (&cx.x)[e], cre = (&cr.x)[e];
      bool diag = (gi == gj);
      float vx = diag ? 1.0f : cxe / (sdi * sdx[b * CN + gj]);
      float vr = diag ? 1.0f : cre / (sri * sdr[b * CN + gj]);
      float vl = cxe + (diag ? 0.001f : 0.0f);
      (&ox.x)[e] = vx; (&orr.x)[e] = vr; (&ol.x)[e] = vl;
      tx[row][c + e] = vx; tr2[row][c + e] = vr; tl[row][c + e] = vl;
    }
    *(float4*)&covx[src + c] = ox;
    *(float4*)&covr[src + c] = orr;
    *(float4*)&Lm[src + c] = ol;
    *(float4*)&Wtri[src + c] = zz;
  }
  if (ti != tj) {
    __syncthreads();
    size_t dst = (size_t)b * PB + (size_t)(tj * 64 + row) * CN + ti * 64;
#pragma unroll
    for (int q = 0; q < 4; ++q) {
      int c = c0 + q * 4;
      float4 ox, orr, ol;
#pragma unroll
      for (int e = 0; e < 4; ++e) {
        (&ox.x)[e] = tx[c + e][row];
        (&orr.x)[e] = tr2[c + e][row];
        (&ol.x)[e] = tl[c + e][row];
      }
      *(float4*)&covx[dst + c] = ox;
      *(float4*)&covr[dst + c] = orr;
      *(float4*)&Lm[dst + c] = ol;
      *(float4*)&Wtri[dst + c] = zz;
    }
  }
}

// ---------------- wave-level 64x64 SPD chol + scaled inverse (lane = column) ----------------
// a[64] stays in REGISTERS (readlane source); the inverse v lives in LDS as a
// lane-private column vout[r][lane] (stride 65 -> conflict-free) to halve register
// pressure (r7's a[64]+v[64]=128-reg layout spilled to scratch: 96 VGPR + FETCH 3.1MB).
// Same verified LDL math as r7 (absmax 0.0): deferred scaling, unit-lower inverse by
// forward substitution, rows scaled by 1/sqrt(d_r). Wave-internal LDS dependencies
// are ordered by compiler-inserted lgkmcnt waits; no barriers needed.
__device__ __forceinline__ void chol_inv64_wave(float a[64], float (*vout)[65], int lane) {
  // factorization: column c frozen at step c (f = 0 for lane <= i)
#pragma unroll
  for (int i = 0; i < 64; ++i) {
    float dinv = 1.0f / rdlane(a[i], i);
    float f = (lane > i) ? a[i] * dinv : 0.0f;   // A'[i][c]/d_i (symmetry: = A'[c][i]/d_i)
#pragma unroll
    for (int r = i + 1; r < 64; ++r)
      a[r] = fmaf(-f, rdlane(a[r], i), a[r]);
  }
  // forward substitution in LDS: M v = e_c, M unit lower with M[r][k] = a_k[r]/d_k
#pragma unroll
  for (int r = 0; r < 64; ++r) vout[r][lane] = (r == lane) ? 1.0f : 0.0f;
#pragma unroll
  for (int k = 0; k < 64; ++k) {
    float g = vout[k][lane] * (1.0f / rdlane(a[k], k));
#pragma unroll
    for (int r = k + 1; r < 64; ++r)
      vout[r][lane] = fmaf(-rdlane(a[r], k), g, vout[r][lane]);
  }
  // scale rows by 1/sqrt(d_r); zero above diagonal
#pragma unroll
  for (int r = 0; r < 64; ++r) {
    float dr = sqrtf(rdlane(a[r], r));
    vout[r][lane] = (r >= lane) ? vout[r][lane] / dr : 0.0f;
  }
}

// ---------------- 128x128 diag block: chol + full inverse W128 = L128^{-1} ----------------
// W128 = [[W11, 0], [W21, W22]]; wave 0 runs the serial 64-chols barrier-free directly
// into the W11s/W22s LDS buffers; all 4 waves run the LDS matmuls (L21, A22', T, W21).
__global__ __launch_bounds__(256, 1) void chol_diag128(const float* __restrict__ A,
                                                       float* __restrict__ Winv, int kstep) {
  int b = blockIdx.x;
  const float* Ab = A + (size_t)b * PB + (size_t)(kstep * 128) * CN + kstep * 128;
  float* Wb = Winv + (size_t)b * 65536 + (size_t)kstep * 16384;
  const int tid = threadIdx.x;
  const int lane = tid & 63;
  const int wv = tid >> 6;
  const int r = tid >> 2, s = tid & 3, c0 = s * 16;
  __shared__ float W11s[64][65], L21s[64][65], W22s[64][65], Ts[64][65];
  float a[64];

  // ---- A11 -> W11 (wave 0 only; barrier-free, output directly in W11s) ----
  if (wv == 0) {
#pragma unroll
    for (int q = 0; q < 64; ++q) a[q] = Ab[(size_t)q * CN + lane];   // coalesced per q
    chol_inv64_wave(a, W11s, lane);
#pragma unroll
    for (int q = 0; q < 64; ++q) {
      Wb[(size_t)q * 128 + lane] = W11s[q][lane];
      Wb[(size_t)q * 128 + 64 + lane] = 0.f;     // zero top-right block
    }
  }
  // stage A21 into Ts (all waves, (r,c0) mapping)
#pragma unroll
  for (int q = 0; q < 4; ++q) {
    float4 t4 = *(const float4*)&Ab[(size_t)(64 + r) * CN + c0 + q * 4];
    Ts[r][c0+q*4+0]=t4.x; Ts[r][c0+q*4+1]=t4.y; Ts[r][c0+q*4+2]=t4.z; Ts[r][c0+q*4+3]=t4.w;
  }
  __syncthreads();                               // B1: W11s + Ts(A21) ready
  // ---- L21 = A21 * W11^T ----
  float l21[16];
#pragma unroll
  for (int cc = 0; cc < 16; ++cc) l21[cc] = 0.f;
  for (int k = 0; k < 64; ++k) {
    float t = Ts[r][k];
#pragma unroll
    for (int cc = 0; cc < 16; ++cc) l21[cc] = fmaf(t, W11s[c0 + cc][k], l21[cc]);
  }
#pragma unroll
  for (int cc = 0; cc < 16; ++cc) L21s[r][c0 + cc] = l21[cc];
  __syncthreads();                               // B2: L21s ready, Ts(A21) reads done
  // ---- A22' = A22 - L21 L21^T -> stage into Ts ----
  float a16[16];
#pragma unroll
  for (int q = 0; q < 4; ++q) {
    float4 t4 = *(const float4*)&Ab[(size_t)(64 + r) * CN + 64 + c0 + q * 4];
    a16[q*4+0]=t4.x; a16[q*4+1]=t4.y; a16[q*4+2]=t4.z; a16[q*4+3]=t4.w;
  }
  for (int k = 0; k < 64; ++k) {
    float t = L21s[r][k];
#pragma unroll
    for (int cc = 0; cc < 16; ++cc) a16[cc] = fmaf(-t, L21s[c0 + cc][k], a16[cc]);
  }
#pragma unroll
  for (int cc = 0; cc < 16; ++cc) Ts[r][c0 + cc] = a16[cc];
  __syncthreads();                               // B3: Ts(A22') ready
  // ---- A22' -> W22 (wave 0 only; output directly in W22s) ----
  if (wv == 0) {
#pragma unroll
    for (int q = 0; q < 64; ++q) a[q] = Ts[q][lane];                 // conflict-free cols
    chol_inv64_wave(a, W22s, lane);
#pragma unroll
    for (int q = 0; q < 64; ++q)
      Wb[(size_t)(64 + q) * 128 + 64 + lane] = W22s[q][lane];
  }
  __syncthreads();                               // B4: W22s ready, Ts(A22') reads done
  // ---- T = L21 * W11 -> Ts ----
  float t16[16];
#pragma unroll
  for (int cc = 0; cc < 16; ++cc) t16[cc] = 0.f;
  for (int k = 0; k < 64; ++k) {
    float t = L21s[r][k];
#pragma unroll
    for (int cc = 0; cc < 16; ++cc) t16[cc] = fmaf(t, W11s[k][c0 + cc], t16[cc]);
  }
  __syncthreads();                               // protect Ts until all reads of A22' done
#pragma unroll
  for (int cc = 0; cc < 16; ++cc) Ts[r][c0 + cc] = t16[cc];
  __syncthreads();                               // B5: Ts(T) ready
  // ---- W21 = -W22 * T ----
  float w21[16];
#pragma unroll
  for (int cc = 0; cc < 16; ++cc) w21[cc] = 0.f;
  for (int k = 0; k < 64; ++k) {
    float t = W22s[r][k];
#pragma unroll
    for (int cc = 0; cc < 16; ++cc) w21[cc] = fmaf(t, Ts[k][c0 + cc], w21[cc]);
  }
#pragma unroll
  for (int q = 0; q < 4; ++q) {
    float4 o = make_float4(-w21[q*4+0], -w21[q*4+1], -w21[q*4+2], -w21[q*4+3]);
    *(float4*)&Wb[(size_t)(64 + r) * 128 + c0 + q * 4] = o;
  }
}

// ---------------- panel update: Apan(Mt x 128) = Apan * W128^T, in place ----------------
__global__ __launch_bounds__(256) void gemm_panel(float* __restrict__ A, const float* __restrict__ W) {
  int b = blockIdx.y;
  float* Ab = A + (size_t)b * PB;
  const float* Wb = W + (size_t)b * 65536;
  const int m0 = blockIdx.x * 64;
  const int tid = threadIdx.x;
  const int lane = tid & 63, w = tid >> 6;
  const int tm = w * 16 + (lane >> 4) * 4;
  const int tn = (lane & 15) * 8;
  __shared__ float As[16][68];
  __shared__ float Bs[16][136];
  float acc[4][8];
#pragma unroll
  for (int i = 0; i < 4; ++i)
#pragma unroll
    for (int j = 0; j < 8; ++j) acc[i][j] = 0.f;
  for (int k0 = 0; k0 < 128; k0 += 16) {
    {
      int lm = tid >> 2, lkq = tid & 3;
      float4 v4 = *(const float4*)&Ab[(size_t)(m0 + lm) * CN + k0 + lkq * 4];
      As[lkq*4+0][lm] = v4.x; As[lkq*4+1][lm] = v4.y; As[lkq*4+2][lm] = v4.z; As[lkq*4+3][lm] = v4.w;
    }
#pragma unroll
    for (int h = 0; h < 2; ++h) {
      int idx2 = tid + h * 256;
      int cc = idx2 >> 2, kq = idx2 & 3;
      float4 v4 = *(const float4*)&Wb[(size_t)cc * 128 + k0 + kq * 4];
      Bs[kq*4+0][cc] = v4.x; Bs[kq*4+1][cc] = v4.y; Bs[kq*4+2][cc] = v4.z; Bs[kq*4+3][cc] = v4.w;
    }
    __syncthreads();
#pragma unroll
    for (int kk = 0; kk < 16; ++kk) {
      float a0 = As[kk][tm], a1 = As[kk][tm+1], a2 = As[kk][tm+2], a3 = As[kk][tm+3];
      float b8[8];
#pragma unroll
      for (int j = 0; j < 8; ++j) b8[j] = Bs[kk][tn + j];
#pragma unroll
      for (int j = 0; j < 8; ++j) {
        acc[0][j] = fmaf(a0, b8[j], acc[0][j]);
        acc[1][j] = fmaf(a1, b8[j], acc[1][j]);
        acc[2][j] = fmaf(a2, b8[j], acc[2][j]);
        acc[3][j] = fmaf(a3, b8[j], acc[3][j]);
      }
    }
    __syncthreads();
  }
#pragma unroll
  for (int i = 0; i < 4; ++i) {
    float4 o0 = make_float4(acc[i][0], acc[i][1], acc[i][2], acc[i][3]);
    float4 o1 = make_float4(acc[i][4], acc[i][5], acc[i][6], acc[i][7]);
    *(float4*)&Ab[(size_t)(m0 + tm + i) * CN + tn] = o0;
    *(float4*)&Ab[(size_t)(m0 + tm + i) * CN + tn + 4] = o1;
  }
}

// scatter 128x128 W blocks onto the Wtri diagonal
__global__ void wdiag128_k(const float* __restrict__ Winv, float* __restrict__ W) {
  int e = blockIdx.x * 256 + threadIdx.x;   // CB * 65536 total
  int b = e >> 16;
  int r2 = e & 65535;
  int blk = r2 >> 14;
  int idx = r2 & 16383;
  int row = idx >> 7, col = idx & 127;
  W[(size_t)b * PB + (size_t)(blk * 128 + row) * CN + blk * 128 + col] = Winv[e];
}

__global__ void sdp_k(const float* __restrict__ prec, float* __restrict__ sdp) {
  int idx = blockIdx.x * 256 + threadIdx.x;
  int b = idx >> 9, i = idx & (CN - 1);
  sdp[idx] = sqrtf(fmaxf(prec[(size_t)b * PB + (size_t)i * (CN + 1)], EPSF));
}

// tile-pair partial-corr with mirror + fused similarity sums
__global__ __launch_bounds__(256) void pc_fuse(float* __restrict__ prec, const float* __restrict__ sdp,
                                               const float* __restrict__ covx, const float* __restrict__ covr,
                                               float* __restrict__ sums) {
  int b = blockIdx.y;
  int p = blockIdx.x, ti = 0;
  while (p >= 8 - ti) { p -= 8 - ti; ++ti; }
  int tj = ti + p;
  __shared__ float tp[64][65];
  int row = threadIdx.x >> 2;
  int c0 = (threadIdx.x & 3) * 16;
  size_t src = (size_t)b * PB + (size_t)(ti * 64 + row) * CN + tj * 64;
  float si = sdp[b * CN + ti * 64 + row];
  int gi = ti * 64 + row;
  float pp = 0.f, ss = 0.f, cc = 0.f, ps = 0.f, pcv = 0.f, sc = 0.f;
#pragma unroll
  for (int q = 0; q < 4; ++q) {
    int c = c0 + q * 4;
    float4 pv = *(const float4*)&prec[src + c];
    float4 px = *(const float4*)&covx[src + c];
    float4 pr = *(const float4*)&covr[src + c];
    float4 ov;
#pragma unroll
    for (int e = 0; e < 4; ++e) {
      int gj = tj * 64 + c + e;
      float arg = (gi == gj) ? 1.0f : -(&pv.x)[e] / (si * sdp[b * CN + gj]);
      float v = tanhf(arg);
      (&ov.x)[e] = v;
      tp[row][c + e] = v;
      if (gj > gi) {
        float P = (&px.x)[e], S = (&pr.x)[e];
        pp += P * P; ss += S * S; cc += v * v;
        ps += P * S; pcv += P * v; sc += S * v;
      }
    }
    *(float4*)&prec[src + c] = ov;
  }
  if (ti != tj) {
    __syncthreads();
    size_t dst = (size_t)b * PB + (size_t)(tj * 64 + row) * CN + ti * 64;
#pragma unroll
    for (int q = 0; q < 4; ++q) {
      int c = c0 + q * 4;
      float4 ov;
#pragma unroll
      for (int e = 0; e < 4; ++e) (&ov.x)[e] = tp[c + e][row];
      *(float4*)&prec[dst + c] = ov;
    }
  }
#pragma unroll
  for (int m = 1; m < 64; m <<= 1) {
    pp += __shfl_xor(pp, m, 64);
    ss += __shfl_xor(ss, m, 64);
    cc += __shfl_xor(cc, m, 64);
    ps += __shfl_xor(ps, m, 64);
    pcv += __shfl_xor(pcv, m, 64);
    sc += __shfl_xor(sc, m, 64);
  }
  if ((threadIdx.x & 63) == 0) {
    atomicAdd(&sums[b * 6 + 0], pp);
    atomicAdd(&sums[b * 6 + 1], ss);
    atomicAdd(&sums[b * 6 + 2], cc);
    atomicAdd(&sums[b * 6 + 3], ps);
    atomicAdd(&sums[b * 6 + 4], pcv);
    atomicAdd(&sums[b * 6 + 5], sc);
  }
}

__global__ void alphas_k(const float* __restrict__ sums, const float* __restrict__ gamma,
                         float* __restrict__ alph) {
  int b = threadIdx.x;
  if (b >= CB) return;
  float sPP = sums[b * 6 + 0], sSS = sums[b * 6 + 1], sCC = sums[b * 6 + 2];
  float sPS = sums[b * 6 + 3], sPC = sums[b * 6 + 4], sSC = sums[b * 6 + 5];
  float numP = 0.5f * (sPS + sPC), numS = 0.5f * (sPS + sSC), numC = 0.5f * (sPC + sSC);
  float noP = 0.5f * sqrtf(sSS + sCC + 2.f * sSC);
  float noS = 0.5f * sqrtf(sPP + sCC + 2.f * sPC);
  float noC = 0.5f * sqrtf(sPP + sSS + 2.f * sPS);
  float dP = fmaxf(sqrtf(sPP), EPSF) * fmaxf(noP, EPSF);
  float dS = fmaxf(sqrtf(sSS), EPSF) * fmaxf(noS, EPSF);
  float dC = fmaxf(sqrtf(sCC), EPSF) * fmaxf(noC, EPSF);
  float g = gamma[0];
  float aP = g * numP / dP, aS = g * numS / dS, aC = g * numC / dC;
  float m = fmaxf(fmaxf(aP, aS), aC);
  float eP = expf(aP - m), eS = expf(aS - m), eC = expf(aC - m);
  float inv = 1.f / (eP + eS + eC);
  alph[b * 3 + 0] = eP * inv;
  alph[b * 3 + 1] = eS * inv;
  alph[b * 3 + 2] = eC * inv;
}

// ---------------- fused: A_fused row + rowsum + LayerNorm features + bf16 pack ----------------
__global__ __launch_bounds__(256) void bfxb_k(const float* __restrict__ Pm, const float* __restrict__ Sm,
                                              const float* __restrict__ Cm, const float* __restrict__ alph,
                                              const float* __restrict__ lng, const float* __restrict__ lnb,
                                              float* __restrict__ Af, float* __restrict__ dinv,
                                              unsigned short* __restrict__ Xpk) {
  int b = blockIdx.y, n = blockIdx.x;
  int tid = threadIdx.x;
  size_t base = (size_t)b * PB + (size_t)n * CN;
  float v[6];
  v[0] = Pm[base + tid];
  v[1] = Pm[base + 256 + tid];
  v[2] = Sm[base + tid];
  v[3] = Sm[base + 256 + tid];
  v[4] = Cm[base + tid];
  v[5] = Cm[base + 256 + tid];
  float ls = 0.f, lq = 0.f;
#pragma unroll
  for (int k = 0; k < 6; ++k) { ls += v[k]; lq += v[k] * v[k]; }
  float aP = alph[b * 3 + 0], aS = alph[b * 3 + 1], aC = alph[b * 3 + 2];
  float af0 = (n == tid) ? 1.0f : aP * v[0] + aS * v[2] + aC * v[4];
  float af1 = (n == 256 + tid) ? 1.0f : aP * v[1] + aS * v[3] + aC * v[5];
  Af[base + tid] = af0;
  Af[base + 256 + tid] = af1;
  float vsum = af0 + af1;
#pragma unroll
  for (int m = 1; m < 64; m <<= 1) {
    ls += __shfl_xor(ls, m, 64);
    lq += __shfl_xor(lq, m, 64);
    vsum += __shfl_xor(vsum, m, 64);
  }
  __shared__ float wls[4], wlq[4], wvs[4];
  int w = tid >> 6;
  if ((tid & 63) == 0) { wls[w] = ls; wlq[w] = lq; wvs[w] = vsum; }
  __syncthreads();
  float tls = wls[0] + wls[1] + wls[2] + wls[3];
  float tlq = wlq[0] + wlq[1] + wlq[2] + wlq[3];
  float tvs = wvs[0] + wvs[1] + wvs[2] + wvs[3];
  if (tid == 0) dinv[b * CN + n] = 1.0f / sqrtf(fmaxf(tvs, EPSF));
  float mu = tls * (1.0f / CIN);
  float var = tlq * (1.0f / CIN) - mu * mu;
  float rstd = 1.0f / sqrtf(var + 1e-5f);
  const size_t XPLANE = (size_t)CB * CN * CIN;
  unsigned short* Xrow = Xpk + ((size_t)b * CN + n) * CIN;
#pragma unroll
  for (int k = 0; k < 6; ++k) {
    int pos = k * 256 + tid;
    float o = (v[k] - mu) * rstd * lng[pos] + lnb[pos];
    unsigned short h = f2bf(o);
    Xrow[pos] = h;
    Xrow[pos + XPLANE] = f2bf(o - bf2f(h));
  }
}

// normalize + pack to bf16 hi/lo planes
__global__ __launch_bounds__(256) void norm_adj_k(const float* __restrict__ AfF, const float* __restrict__ dinv,
                                                  unsigned short* __restrict__ Afp) {
  int b = blockIdx.y;
  int e = blockIdx.x * 256 + threadIdx.x;
  int i = e >> 9, j = e & (CN - 1);
  size_t off = (size_t)b * PB + e;
  float v = AfF[off] * dinv[b * CN + i] * dinv[b * CN + j];
  unsigned short h = f2bf(v);
  Afp[off] = h;
  Afp[off + SBNN] = f2bf(v - bf2f(h));
}

// ---------------- head: two-stage mean-pool + classifier + sigmoid ----------------
__global__ __launch_bounds__(256) void head1_k(const float* __restrict__ H, const float* __restrict__ Wc,
                                               float* __restrict__ logit) {
  int b = blockIdx.x, c = blockIdx.y;
  int d = threadIdx.x;
  const float* Hb = H + (size_t)b * CN * CD + (size_t)c * 64 * CD;
  float s0 = 0.f, s1 = 0.f;
  for (int n = 0; n < 64; ++n) {
    s0 += Hb[(size_t)n * CD + d];
    s1 += Hb[(size_t)n * CD + 256 + d];
  }
  __shared__ float red[256];
  red[d] = s0 * Wc[d] + s1 * Wc[256 + d];
  __syncthreads();
  for (int k = 128; k > 0; k >>= 1) {
    if (d < k) red[d] += red[d + k];
    __syncthreads();
  }
  if (d == 0) atomicAdd(&logit[b], red[0]);
}

__global__ void sig_k(const float* __restrict__ logit, const float* __restrict__ bc, float* __restrict__ out) {
  int b = threadIdx.x;
  if (b < CB) out[b] = 1.0f / (1.0f + expf(-(logit[b] * (1.0f / CN) + bc[0])));
}

// ---------------- launcher ----------------
extern "C" void kernel_launch(void* const* d_in, const int* in_sizes, int n_in,
                              void* d_out, int out_size, void* d_ws, size_t ws_size,
                              hipStream_t stream) {
  const float* x    = (const float*)d_in[0];
  const float* gam  = (const float*)d_in[1];
  const float* lng  = (const float*)d_in[2];
  const float* lnb  = (const float*)d_in[3];
  const float* W0   = (const float*)d_in[4];
  const float* b0   = (const float*)d_in[5];
  const float* W1   = (const float*)d_in[6];
  const float* b1   = (const float*)d_in[7];
  const float* W2   = (const float*)d_in[8];
  const float* b2   = (const float*)d_in[9];
  const float* Wc   = (const float*)d_in[10];
  const float* bc   = (const float*)d_in[11];
  float* out = (float*)d_out;
  float* ws = (float*)d_ws;

  unsigned short* Xtp = (unsigned short*)ws;
  float* Winv8 = ws;                      // 16 x 65536 floats (4 MB); Xtp slots 0-5 dead after cov
  float* Ttmp  = ws + 1048576;            // after Winv8
  float* covx  = ws + 16777216;
  float* covr  = covx + SBNN;
  float* Lm    = covx + 2 * SBNN;
  float* Wtri  = covx + 3 * SBNN;
  float* prY   = covx + 4 * SBNN;
  float* sdx   = covx + 5 * SBNN;
  float* sdr   = sdx + 8192;
  float* sdp   = sdr + 8192;
  float* dinv  = sdp + 8192;
  float* gm    = dinv + 8192;
  float* ms    = gm + 8192;
  float* sums  = ms + 8192;
  float* alph  = sums + 96;
  float* logit = alph + 48;

  unsigned short* Xpk  = (unsigned short*)ws;
  unsigned short* Afp  = (unsigned short*)(ws + 12582912);
  float*          AfF  = Lm;
  unsigned short* Wp   = (unsigned short*)Lm;   // bf16 hi/lo pack of Wtri for MFMA SYRK
  unsigned short* w0t  = (unsigned short*)Lm;
  unsigned short* w1t  = (unsigned short*)(Lm + 1048576);
  unsigned short* w2t  = (unsigned short*)(Lm + 1572864);
  unsigned short* Zt1  = (unsigned short*)prY;
  unsigned short* Zt2  = (unsigned short*)Wtri;
  unsigned short* Zt3  = (unsigned short*)prY;
  unsigned short* H1p  = (unsigned short*)covx;
  unsigned short* H2p  = (unsigned short*)covr;
  float*          Ha   = covx;

  const float covscale = (float)(1.0 / 1023.00000001);
  const long long sPB = (long long)PB;

  zero_k<<<(8352 + 255) / 256, 256, 0, stream>>>(ms, 8352);
  colmean_k<<<dim3(2, CB, 4), 256, 0, stream>>>(x, ms);
  cpack_k<<<dim3(8, 16, CB), 256, 0, stream>>>(x, ms, Xtp);
  ranks_k<<<dim3(CN / 8, CB), 512, 0, stream>>>(x, Xtp);

  // both covariances via bf16-split MFMA, triangular tile grid
  gemm_mfma<true, false, false, true><<<dim3(10, 1, 32), 256, 0, stream>>>(
      Xtp, Xtp, nullptr, covx, 1024, 1024, 1024, CN,
      524288LL, 524288LL, sPB, PLX, PLX, 0LL, covscale);
  sds_k<<<32, 256, 0, stream>>>(covx, covr, sdx, sdr);
  prep_mirror<<<dim3(36, CB), 256, 0, stream>>>(covx, covr, sdx, sdr, Lm, Wtri);

  // blocked Cholesky, NB=128: 4 diag + 3 panel + 3 trailing dispatches
  for (int k = 0; k < 4; ++k) {
    chol_diag128<<<CB, 256, 0, stream>>>(Lm, Winv8, k);
    int Mt = CN - 128 * (k + 1);
    if (Mt > 0) {
      float* Apan = Lm + (size_t)(k + 1) * 128 * CN + k * 128;
      float* Atrl = Lm + (size_t)(k + 1) * 128 * CN + (k + 1) * 128;
      gemm_panel<<<dim3(Mt / 64, CB), 256, 0, stream>>>(Apan, Winv8 + (size_t)k * 16384);
      int nb = Mt / 64;
      gemm_k<false, true, true, false, false, true><<<dim3(nb * (nb + 1) / 2, 1, CB), 256, 0, stream>>>(
          Apan, Apan, nullptr, Atrl, Mt, Mt, 128, CN, CN, CN,
          sPB, sPB, sPB, -1.0f, 1, 0, 0, 0);
    }
  }

  // W = L^{-1}: scatter 128-diag W blocks + 2 merge levels (128->256->512)
  wdiag128_k<<<4096, 256, 0, stream>>>(Winv8, Wtri);
  gemm_k<false, false, false, false><<<dim3(2, 2, CB * 2), 256, 0, stream>>>(
      Lm + 128 * CN, Wtri, nullptr, Ttmp, 128, 128, 128, CN, CN, 128,
      sPB, sPB, 32768LL, 1.0f, 2, 131328LL, 131328LL, 16384LL);
  gemm_k<false, false, false, false><<<dim3(2, 2, CB * 2), 256, 0, stream>>>(
      Wtri + 128 * CN + 128, Ttmp, nullptr, Wtri + 128 * CN, 128, 128, 128, CN, 128, CN,
      sPB, 32768LL, sPB, -1.0f, 2, 131328LL, 16384LL, 131328LL);
  gemm_k<false, false, false, false><<<dim3(4, 4, CB), 256, 0, stream>>>(
      Lm + 256 * CN, Wtri, nullptr, Ttmp, 256, 256, 256, CN, CN, 256,
      sPB, sPB, 65536LL, 1.0f, 1, 0, 0, 0);
  gemm_k<false, false, false, false><<<dim3(4, 4, CB), 256, 0, stream>>>(
      Wtri + 256 * CN + 256, Ttmp, nullptr, Wtri + 256 * CN, 256, 256, 256, CN, 256, CN,
      sPB, 65536LL, sPB, -1.0f, 1, 0, 0, 0);

  // prec = W^T W via bf16-split MFMA (triangular grid; mirror + fused sums in pc_fuse)
  wpackb_k<<<dim3(8, 8, CB), 256, 0, stream>>>(Wtri, Wp);
  gemm_mfma<true, false, false, true><<<dim3(10, 1, CB), 256, 0, stream>>>(
      Wp, Wp, nullptr, prY, CN, CN, CN, CN,
      262144LL, 262144LL, sPB, 4194304LL, 4194304LL, 0LL, 1.0f);
  sdp_k<<<32, 256, 0, stream>>>(prY, sdp);
  pc_fuse<<<dim3(36, CB), 256, 0, stream>>>(prY, sdp, covx, covr, sums);

  alphas_k<<<1, 64, 0, stream>>>(sums, gam, alph);
  bfxb_k<<<dim3(CN, CB), 256, 0, stream>>>(covx, covr, prY, alph, lng, lnb, AfF, dinv, Xpk);
  norm_adj_k<<<dim3(1024, CB), 256, 0, stream>>>(AfF, dinv, Afp);

  wpack_k<<<dim3(24, 8), 256, 0, stream>>>(W0, w0t, CIN, CD, 786432LL);
  wpack_k<<<dim3(8, 8), 256, 0, stream>>>(W1, w1t, CD, CD, 262144LL);
  wpack_k<<<dim3(8, 8), 256, 0, stream>>>(W2, w2t, CD, CD, 262144LL);

  // GCN via bf16-split MFMA (128x128 tiles; orientation alternates, no transposes)
  gemm_mfma<false, false, true><<<dim3(64, 4, 1), 256, 0, stream>>>(
      w0t, Xpk, b0, Zt1, CIN, CIN, CIN, 8192, 0, 0, 0, 786432LL, 12582912LL, 4194304LL, 1.0f);
  gemm_mfma<false, true, false><<<dim3(4, 4, CB), 256, 0, stream>>>(
      Afp, Zt1, nullptr, H1p, CN, CN, 8192, CD, 262144LL, 512LL, 262144LL,
      4194304LL, 4194304LL, 4194304LL, 1.0f);
  gemm_mfma<false, false, true><<<dim3(64, 4, 1), 256, 0, stream>>>(
      w1t, H1p, b1, Zt2, CD, CD, CD, 8192, 0, 0, 0, 262144LL, 4194304LL, 4194304LL, 1.0f);
  gemm_mfma<false, true, false><<<dim3(4, 4, CB), 256, 0, stream>>>(
      Afp, Zt2, nullptr, H2p, CN, CN, 8192, CD, 262144LL, 512LL, 262144LL,
      4194304LL, 4194304LL, 4194304LL, 1.0f);
  gemm_mfma<false, false, true><<<dim3(64, 4, 1), 256, 0, stream>>>(
      w2t, H2p, b2, Zt3, CD, CD, CD, 8192, 0, 0, 0, 262144LL, 4194304LL, 4194304LL, 1.0f);
  gemm_mfma<true, true, false><<<dim3(4, 4, CB), 256, 0, stream>>>(
      Afp, Zt3, nullptr, Ha, CN, CN, 8192, CD, 262144LL, 512LL, 262144LL,
      4194304LL, 4194304LL, 0LL, 1.0f);

  head1_k<<<dim3(CB, 8), 256, 0, stream>>>(Ha, Wc, logit);
  sig_k<<<1, 64, 0, stream>>>(logit, bc, out);
}